// Round 21
// baseline (132.223 us; speedup 1.0000x reference)
//
#include <hip/hip_runtime.h>
#include <hip/hip_bf16.h>

#define NB 4
#define SL 2048
#define NG 16
#define NH 8
#define DH 64
#define NBH (NB * NH)
#define NCH (SL / 64)  // 32 chunks of 64

typedef __attribute__((ext_vector_type(8))) short bh8;
typedef __attribute__((ext_vector_type(4))) float fx4;

__device__ __forceinline__ ushort f2bf(float x) {
    union { float f; unsigned u; } v; v.f = x;
    const unsigned r = v.u + 0x7fffu + ((v.u >> 16) & 1u);  // RNE
    return (ushort)(r >> 16);
}
__device__ __forceinline__ float b2f(ushort u) {
    union { unsigned u; float f; } v; v.u = ((unsigned)u) << 16;
    return v.f;
}
__device__ __forceinline__ bh8 pack8(float4 lo, float4 hi) {
    bh8 r;
    r[0] = (short)f2bf(lo.x); r[1] = (short)f2bf(lo.y);
    r[2] = (short)f2bf(lo.z); r[3] = (short)f2bf(lo.w);
    r[4] = (short)f2bf(hi.x); r[5] = (short)f2bf(hi.y);
    r[6] = (short)f2bf(hi.z); r[7] = (short)f2bf(hi.w);
    return r;
}
__device__ __forceinline__ void unpack8(bh8 v, float4& lo, float4& hi) {
    lo.x = b2f((ushort)v[0]); lo.y = b2f((ushort)v[1]);
    lo.z = b2f((ushort)v[2]); lo.w = b2f((ushort)v[3]);
    hi.x = b2f((ushort)v[4]); hi.y = b2f((ushort)v[5]);
    hi.z = b2f((ushort)v[6]); hi.w = b2f((ushort)v[7]);
}
// swizzle: within a 64-elem (128B) row, XOR elem bits 3..5 with row&7.
__device__ __forceinline__ int swz(int row, int col) {
    return row * 64 + (col ^ ((row & 7) << 3));
}

// ---------------------------------------------------------------------------
// prep: z<5 -> weight transpose f32->bf16 (tile 32x32), incl. cp.
//       z==5 -> context f32->bf16 (16 blocks).
// grid (16,16,6).
// ---------------------------------------------------------------------------
__global__ __launch_bounds__(256) void prep_kernel(
    const float* __restrict__ w0, const float* __restrict__ w1,
    const float* __restrict__ w2, const float* __restrict__ w3,
    const float* __restrict__ w4, const float* __restrict__ context,
    ushort* __restrict__ o0, ushort* __restrict__ o1,
    ushort* __restrict__ o2, ushort* __restrict__ o3,
    ushort* __restrict__ o4, ushort* __restrict__ ctxb) {
    const int z = blockIdx.z;
    const int t = threadIdx.x;
    if (z < 5) {
        const float* W = (z == 0) ? w0 : (z == 1) ? w1 : (z == 2) ? w2
                       : (z == 3) ? w3 : w4;
        ushort* WT = (z == 0) ? o0 : (z == 1) ? o1 : (z == 2) ? o2
                   : (z == 3) ? o3 : o4;
        __shared__ float tile[32][33];
        const int bx = blockIdx.x * 32, by = blockIdx.y * 32;
        const int tx = t & 31, ty = t >> 5;
#pragma unroll
        for (int p = 0; p < 4; ++p)
            tile[ty + p * 8][tx] = W[(size_t)(by + ty + p * 8) * 512 + bx + tx];
        __syncthreads();
#pragma unroll
        for (int p = 0; p < 4; ++p)
            WT[(size_t)(bx + ty + p * 8) * 512 + by + tx] = f2bf(tile[tx][ty + p * 8]);
    } else {
        if (blockIdx.x != 0 || blockIdx.y >= 16) return;
        const int idx = (blockIdx.y * 256 + t) * 8;  // 16*256*8 = 32768 elems
        const float4 lo = *(const float4*)&context[idx];
        const float4 hi = *(const float4*)&context[idx + 4];
        *(bh8*)&ctxb[idx] = pack8(lo, hi);
    }
}

// ---------------------------------------------------------------------------
// Context projection via MFMA: ctxb (64x512 bf16) @ cpT^T -> cs f32 heads.
// 64x128 tile, BK=64, swizzled LDS, counted-vmcnt pipeline.  grid (4).
// ---------------------------------------------------------------------------
__global__ __launch_bounds__(256) void gemm_ctx_kernel(const ushort* __restrict__ A,
                                                       const ushort* __restrict__ BT,
                                                       float* __restrict__ cs) {
    __shared__ __align__(16) ushort As[2][64 * 64];
    __shared__ __align__(16) ushort Bs[2][128 * 64];
    const int t = threadIdx.x;
    const int lane = t & 63, w = t >> 6;
    const int bn = blockIdx.x * 128;
    size_t asrc[2], bsrc[4];
#pragma unroll
    for (int i = 0; i < 2; ++i) {
        const int s = w * 1024 + i * 512 + lane * 8;
        const int r = s >> 6, o = (s & 63) ^ ((r & 7) << 3);
        asrc[i] = (size_t)r * 512 + o;
    }
#pragma unroll
    for (int i = 0; i < 4; ++i) {
        const int s = w * 2048 + i * 512 + lane * 8;
        const int r = s >> 6, o = (s & 63) ^ ((r & 7) << 3);
        bsrc[i] = (size_t)(bn + r) * 512 + o;
    }
    const int wr = w >> 1, wc = w & 1;
    const int fr = lane & 15, kg = lane >> 4;
    fx4 acc[2][4] = {};

#define STAGE_C(buf, kk)                                                       \
    do {                                                                       \
        _Pragma("unroll")                                                      \
        for (int i = 0; i < 2; ++i)                                            \
            __builtin_amdgcn_global_load_lds(                                  \
                (const __attribute__((address_space(1))) void*)(A + asrc[i] + (kk)), \
                (__attribute__((address_space(3))) void*)&As[buf][w * 1024 + i * 512], \
                16, 0, 0);                                                     \
        _Pragma("unroll")                                                      \
        for (int i = 0; i < 4; ++i)                                            \
            __builtin_amdgcn_global_load_lds(                                  \
                (const __attribute__((address_space(1))) void*)(BT + bsrc[i] + (kk)), \
                (__attribute__((address_space(3))) void*)&Bs[buf][w * 2048 + i * 512], \
                16, 0, 0);                                                     \
    } while (0)

    STAGE_C(0, 0);
    STAGE_C(1, 64);
    asm volatile("s_waitcnt vmcnt(6)" ::: "memory");
    __builtin_amdgcn_s_barrier();
    __builtin_amdgcn_sched_barrier(0);
    int cur = 0;
    for (int k0 = 0; k0 < 512; k0 += 64) {
#pragma unroll
        for (int kk = 0; kk < 2; ++kk) {
            bh8 af[2], bf[4];
#pragma unroll
            for (int m = 0; m < 2; ++m) {
                const int R = wr * 32 + m * 16 + fr;
                af[m] = *(const bh8*)&As[cur][swz(R, kk * 32 + kg * 8)];
            }
#pragma unroll
            for (int nn = 0; nn < 4; ++nn) {
                const int C = wc * 64 + nn * 16 + fr;
                bf[nn] = *(const bh8*)&Bs[cur][swz(C, kk * 32 + kg * 8)];
            }
#pragma unroll
            for (int m = 0; m < 2; ++m)
#pragma unroll
                for (int nn = 0; nn < 4; ++nn)
                    acc[m][nn] = __builtin_amdgcn_mfma_f32_16x16x32_bf16(
                        af[m], bf[nn], acc[m][nn], 0, 0, 0);
        }
        asm volatile("s_waitcnt lgkmcnt(0)" ::: "memory");
        __builtin_amdgcn_s_barrier();
        __builtin_amdgcn_sched_barrier(0);
        if (k0 + 128 < 512) {
            STAGE_C(cur, k0 + 128);
            asm volatile("s_waitcnt vmcnt(6)" ::: "memory");
        } else if (k0 + 64 < 512) {
            asm volatile("s_waitcnt vmcnt(0)" ::: "memory");
        }
        __builtin_amdgcn_sched_barrier(0);
        cur ^= 1;
    }
#undef STAGE_C
#pragma unroll
    for (int m = 0; m < 2; ++m)
#pragma unroll
        for (int nn = 0; nn < 4; ++nn)
#pragma unroll
            for (int j = 0; j < 4; ++j) {
                const int r = wr * 32 + m * 16 + kg * 4 + j;   // 0..63 = b*NG+i
                const int cc = bn + wc * 64 + nn * 16 + fr;
                const int b = r >> 4, i = r & 15;
                cs[(((size_t)(b * NH) + (cc >> 6)) * NG + i) * DH + (cc & 63)] =
                    acc[m][nn][j];
            }
}

// ---------------------------------------------------------------------------
// QKV MFMA GEMM, fused f32->bf16 of A.  64x128 tile, BK=64, swizzled LDS,
// raw-barrier + counted vmcnt + 2-deep A-register pipeline.  grid (128,4,3).
// NOTE: grid.x must stay ≡ 0 (mod 8): blocks sharing an A-panel (same x,
// different y) sit at linear stride grid.x; stride % 8 == 0 keeps them on
// one XCD so A re-reads hit L2 (R19: stride 129 -> FETCH 42->105 MB).
// ---------------------------------------------------------------------------
__global__ __launch_bounds__(256, 3) void gemm_qkv_kernel(
    const float* __restrict__ qf, const float* __restrict__ kf,
    const float* __restrict__ vf, const ushort* __restrict__ qpT,
    const ushort* __restrict__ kpT, const ushort* __restrict__ vpT,
    ushort* __restrict__ qsb, ushort* __restrict__ ksb, ushort* __restrict__ vsb) {
    const int z = blockIdx.z;
    const float* A32 = (z == 0) ? qf : (z == 1) ? kf : vf;
    const ushort* BT = (z == 0) ? qpT : (z == 1) ? kpT : vpT;
    ushort* out = (z == 0) ? qsb : (z == 1) ? ksb : vsb;

    __shared__ __align__(16) ushort As[2][64 * 64];
    __shared__ __align__(16) ushort Bs[2][128 * 64];
    const int t = threadIdx.x;
    const int lane = t & 63, w = t >> 6;
    const int bm = blockIdx.x * 64, bn = blockIdx.y * 128;
    const int ar = t >> 2, ao = (t & 3) * 16;
    const size_t abase = (size_t)(bm + ar) * 512 + ao;
    const int asw0 = swz(ar, ao), asw1 = swz(ar, ao + 8);
    size_t bsrc[4];
#pragma unroll
    for (int i = 0; i < 4; ++i) {
        const int s = w * 2048 + i * 512 + lane * 8;
        const int r = s >> 6, o = (s & 63) ^ ((r & 7) << 3);
        bsrc[i] = (size_t)(bn + r) * 512 + o;
    }
    const int wr = w >> 1, wc = w & 1;
    const int fr = lane & 15, kg = lane >> 4;
    fx4 acc[2][4] = {};
    float4 a00, a01, a02, a03;   // A register set 0
    float4 a10, a11, a12, a13;   // A register set 1

#define LOADA0(kk)                                                             \
    do {                                                                       \
        a00 = *(const float4*)&A32[abase + (kk)];                              \
        a01 = *(const float4*)&A32[abase + (kk) + 4];                          \
        a02 = *(const float4*)&A32[abase + (kk) + 8];                          \
        a03 = *(const float4*)&A32[abase + (kk) + 12];                         \
    } while (0)
#define LOADA1(kk)                                                             \
    do {                                                                       \
        a10 = *(const float4*)&A32[abase + (kk)];                              \
        a11 = *(const float4*)&A32[abase + (kk) + 4];                          \
        a12 = *(const float4*)&A32[abase + (kk) + 8];                          \
        a13 = *(const float4*)&A32[abase + (kk) + 12];                         \
    } while (0)
#define WRITEA0(buf)                                                           \
    do {                                                                       \
        *(bh8*)&As[buf][asw0] = pack8(a00, a01);                               \
        *(bh8*)&As[buf][asw1] = pack8(a02, a03);                               \
    } while (0)
#define WRITEA1(buf)                                                           \
    do {                                                                       \
        *(bh8*)&As[buf][asw0] = pack8(a10, a11);                               \
        *(bh8*)&As[buf][asw1] = pack8(a12, a13);                               \
    } while (0)
#define STAGEB(buf, kk)                                                        \
    do {                                                                       \
        _Pragma("unroll")                                                      \
        for (int i = 0; i < 4; ++i)                                            \
            __builtin_amdgcn_global_load_lds(                                  \
                (const __attribute__((address_space(1))) void*)(BT + bsrc[i] + (kk)), \
                (__attribute__((address_space(3))) void*)&Bs[buf][w * 2048 + i * 512], \
                16, 0, 0);                                                     \
    } while (0)
#define MFMA_PHASE(buf)                                                        \
    do {                                                                       \
        _Pragma("unroll")                                                      \
        for (int kk = 0; kk < 2; ++kk) {                                       \
            bh8 af[2], bf[4];                                                  \
            _Pragma("unroll")                                                  \
            for (int m = 0; m < 2; ++m) {                                      \
                const int R = wr * 32 + m * 16 + fr;                           \
                af[m] = *(const bh8*)&As[buf][swz(R, kk * 32 + kg * 8)];       \
            }                                                                  \
            _Pragma("unroll")                                                  \
            for (int nn = 0; nn < 4; ++nn) {                                   \
                const int C = wc * 64 + nn * 16 + fr;                          \
                bf[nn] = *(const bh8*)&Bs[buf][swz(C, kk * 32 + kg * 8)];      \
            }                                                                  \
            _Pragma("unroll")                                                  \
            for (int m = 0; m < 2; ++m)                                        \
                _Pragma("unroll")                                              \
                for (int nn = 0; nn < 4; ++nn)                                 \
                    acc[m][nn] = __builtin_amdgcn_mfma_f32_16x16x32_bf16(      \
                        af[m], bf[nn], acc[m][nn], 0, 0, 0);                   \
        }                                                                      \
    } while (0)

    // prologue: buf0 fully staged; B(64) in flight; A(64)->set1, A(128)->set0
    STAGEB(0, 0);
    LOADA0(0);
    WRITEA0(0);                      // compiler drains A(0) loads
    LOADA1(64);
    LOADA0(128);
    STAGEB(1, 64);
    asm volatile("s_waitcnt vmcnt(12) lgkmcnt(0)" ::: "memory");  // B(0) done
    __builtin_amdgcn_s_barrier();
    __builtin_amdgcn_sched_barrier(0);

#pragma unroll
    for (int p = 0; p < 8; ++p) {
        const int k0 = p * 64;
        const int buf = p & 1;
        MFMA_PHASE(buf);
        if (p < 7) {                 // pack A(k0+64), loaded TWO phases ago
            if (((p + 1) & 1) == 0) WRITEA0(buf ^ 1);
            else                    WRITEA1(buf ^ 1);
        }
        asm volatile("s_waitcnt lgkmcnt(0)" ::: "memory");
        __builtin_amdgcn_s_barrier();
        __builtin_amdgcn_sched_barrier(0);
        if (p <= 5) STAGEB(buf, k0 + 128);   // restage buffer just read
        if (p <= 4) {                        // A(k0+192) into freed set
            if (((p + 1) & 1) == 0) LOADA0(k0 + 192);
            else                    LOADA1(k0 + 192);
        }
        if (p <= 4)      asm volatile("s_waitcnt vmcnt(12)" ::: "memory");
        else if (p == 5) asm volatile("s_waitcnt vmcnt(8)" ::: "memory");
        else if (p == 6) asm volatile("s_waitcnt vmcnt(0)" ::: "memory");
        __builtin_amdgcn_sched_barrier(0);
    }
#undef LOADA0
#undef LOADA1
#undef WRITEA0
#undef WRITEA1
#undef STAGEB
#undef MFMA_PHASE
#pragma unroll
    for (int m = 0; m < 2; ++m)
#pragma unroll
        for (int nn = 0; nn < 4; ++nn)
#pragma unroll
            for (int j = 0; j < 4; ++j) {
                const int r = bm + wr * 32 + m * 16 + kg * 4 + j;
                const int cc = bn + wc * 64 + nn * 16 + fr;
                const int b = r >> 11, i = r & 2047;  // SL = 2048
                out[(((size_t)(b * NH) + (cc >> 6)) * SL + i) * DH + (cc & 63)] =
                    f2bf(acc[m][nn][j]);
            }
}

// ---------------------------------------------------------------------------
// Output MFMA GEMM: ohb (8192x512 bf16) @ opT^T -> f32 plain.
// 64x128 tile, BK=64, swizzled LDS, counted-vmcnt pipeline.  grid (128,4).
// ---------------------------------------------------------------------------
__global__ __launch_bounds__(256, 3) void gemm_out_kernel(const ushort* __restrict__ A,
                                                          const ushort* __restrict__ BT,
                                                          float* __restrict__ out) {
    __shared__ __align__(16) ushort As[2][64 * 64];
    __shared__ __align__(16) ushort Bs[2][128 * 64];
    const int t = threadIdx.x;
    const int lane = t & 63, w = t >> 6;
    const int bm = blockIdx.x * 64, bn = blockIdx.y * 128;
    size_t asrc[2], bsrc[4];
#pragma unroll
    for (int i = 0; i < 2; ++i) {
        const int s = w * 1024 + i * 512 + lane * 8;
        const int r = s >> 6, o = (s & 63) ^ ((r & 7) << 3);
        asrc[i] = (size_t)(bm + r) * 512 + o;
    }
#pragma unroll
    for (int i = 0; i < 4; ++i) {
        const int s = w * 2048 + i * 512 + lane * 8;
        const int r = s >> 6, o = (s & 63) ^ ((r & 7) << 3);
        bsrc[i] = (size_t)(bn + r) * 512 + o;
    }
    const int wr = w >> 1, wc = w & 1;
    const int fr = lane & 15, kg = lane >> 4;
    fx4 acc[2][4] = {};

#define STAGE_O(buf, kk)                                                       \
    do {                                                                       \
        _Pragma("unroll")                                                      \
        for (int i = 0; i < 2; ++i)                                            \
            __builtin_amdgcn_global_load_lds(                                  \
                (const __attribute__((address_space(1))) void*)(A + asrc[i] + (kk)), \
                (__attribute__((address_space(3))) void*)&As[buf][w * 1024 + i * 512], \
                16, 0, 0);                                                     \
        _Pragma("unroll")                                                      \
        for (int i = 0; i < 4; ++i)                                            \
            __builtin_amdgcn_global_load_lds(                                  \
                (const __attribute__((address_space(1))) void*)(BT + bsrc[i] + (kk)), \
                (__attribute__((address_space(3))) void*)&Bs[buf][w * 2048 + i * 512], \
                16, 0, 0);                                                     \
    } while (0)

    STAGE_O(0, 0);
    STAGE_O(1, 64);
    asm volatile("s_waitcnt vmcnt(6)" ::: "memory");  // buf0's 6 ops done
    __builtin_amdgcn_s_barrier();
    __builtin_amdgcn_sched_barrier(0);
    int cur = 0;
    for (int k0 = 0; k0 < 512; k0 += 64) {
#pragma unroll
        for (int kk = 0; kk < 2; ++kk) {
            bh8 af[2], bf[4];
#pragma unroll
            for (int m = 0; m < 2; ++m) {
                const int R = wr * 32 + m * 16 + fr;
                af[m] = *(const bh8*)&As[cur][swz(R, kk * 32 + kg * 8)];
            }
#pragma unroll
            for (int nn = 0; nn < 4; ++nn) {
                const int C = wc * 64 + nn * 16 + fr;
                bf[nn] = *(const bh8*)&Bs[cur][swz(C, kk * 32 + kg * 8)];
            }
#pragma unroll
            for (int m = 0; m < 2; ++m)
#pragma unroll
                for (int nn = 0; nn < 4; ++nn)
                    acc[m][nn] = __builtin_amdgcn_mfma_f32_16x16x32_bf16(
                        af[m], bf[nn], acc[m][nn], 0, 0, 0);
        }
        asm volatile("s_waitcnt lgkmcnt(0)" ::: "memory");
        __builtin_amdgcn_s_barrier();
        __builtin_amdgcn_sched_barrier(0);
        if (k0 + 128 < 512) {
            STAGE_O(cur, k0 + 128);
            asm volatile("s_waitcnt vmcnt(6)" ::: "memory");
        } else if (k0 + 64 < 512) {
            asm volatile("s_waitcnt vmcnt(0)" ::: "memory");
        }
        __builtin_amdgcn_sched_barrier(0);
        cur ^= 1;
    }
#undef STAGE_O
#pragma unroll
    for (int m = 0; m < 2; ++m)
#pragma unroll
        for (int nn = 0; nn < 4; ++nn)
#pragma unroll
            for (int j = 0; j < 4; ++j) {
                const int r = bm + wr * 32 + m * 16 + kg * 4 + j;
                const int cc = bn + wc * 64 + nn * 16 + fr;
                out[(size_t)r * 512 + cc] = acc[m][nn][j];
            }
}

// ---------------------------------------------------------------------------
// Fused: W = exp(Ks@Cs^T) -> wb (s,g) + wbT (g,s) + per-chunk sums M_c, N_c.
// grid (NBH, NCH).
// ---------------------------------------------------------------------------
__global__ __launch_bounds__(256) void chunk_sums_w_kernel(
    const ushort* __restrict__ ksb, const ushort* __restrict__ vsb,
    const float* __restrict__ cs, float* __restrict__ wb,
    float* __restrict__ wbT, float* __restrict__ Mc, float* __restrict__ Nc) {
    const int bh = blockIdx.x, c = blockIdx.y;
    __shared__ float Ks[64 * 64];
    __shared__ float Vs[64 * 64];
    __shared__ float Ws[64 * 16];
    __shared__ float Cs[16][65];
    const int t = threadIdx.x;
    const ushort* kbase = ksb + ((size_t)bh * SL + c * 64) * DH;
    const ushort* vbase = vsb + ((size_t)bh * SL + c * 64) * DH;
#pragma unroll
    for (int p = 0; p < 2; ++p) {
        const int idx = (p * 256 + t) * 8;
        float4 lo, hi;
        unpack8(*(const bh8*)&kbase[idx], lo, hi);
        *(float4*)&Ks[idx] = lo; *(float4*)&Ks[idx + 4] = hi;
        unpack8(*(const bh8*)&vbase[idx], lo, hi);
        *(float4*)&Vs[idx] = lo; *(float4*)&Vs[idx + 4] = hi;
    }
    {
        const int idx = t * 4;
        const float4 cv = *(const float4*)&cs[(size_t)bh * NG * DH + idx];
        const int g = idx >> 6, e = idx & 63;
        Cs[g][e + 0] = cv.x; Cs[g][e + 1] = cv.y; Cs[g][e + 2] = cv.z; Cs[g][e + 3] = cv.w;
    }
    __syncthreads();
    {
        const int i = (t * 4) >> 4, g0 = (t * 4) & 15;
        float d0 = 0.f, d1 = 0.f, d2 = 0.f, d3 = 0.f;
#pragma unroll 8
        for (int e = 0; e < 64; ++e) {
            const float kv = Ks[i * 64 + e];
            d0 += kv * Cs[g0 + 0][e];
            d1 += kv * Cs[g0 + 1][e];
            d2 += kv * Cs[g0 + 2][e];
            d3 += kv * Cs[g0 + 3][e];
        }
        float4 wv;
        wv.x = expf(d0); wv.y = expf(d1); wv.z = expf(d2); wv.w = expf(d3);
        *(float4*)&Ws[i * 16 + g0] = wv;
        *(float4*)&wb[((size_t)bh * SL + c * 64 + i) * NG + g0] = wv;
    }
    __syncthreads();
    {
        const int g = t >> 4, i0 = (t & 15) * 4;
        float4 wv4;
        wv4.x = Ws[(i0 + 0) * 16 + g];
        wv4.y = Ws[(i0 + 1) * 16 + g];
        wv4.z = Ws[(i0 + 2) * 16 + g];
        wv4.w = Ws[(i0 + 3) * 16 + g];
        *(float4*)&wbT[((size_t)(bh * NG) + g) * SL + c * 64 + i0] = wv4;
    }
    const int e = t >> 2, g0 = (t & 3) * 4;
    float m0 = 0.f, m1 = 0.f, m2 = 0.f, m3 = 0.f;
#pragma unroll 8
    for (int i = 0; i < 64; ++i) {
        const float kv = Ks[i * 64 + e];
        const float4 w = *(const float4*)&Ws[i * 16 + g0];
        m0 += kv * w.x; m1 += kv * w.y; m2 += kv * w.z; m3 += kv * w.w;
    }
    const int g2 = t >> 4, e2 = (t & 15) * 4;
    float n0 = 0.f, n1 = 0.f, n2 = 0.f, n3 = 0.f;
#pragma unroll 8
    for (int i = 0; i < 64; ++i) {
        const float wv = Ws[i * 16 + g2];
        const float4 vv = *(const float4*)&Vs[i * 64 + e2];
        n0 += wv * vv.x; n1 += wv * vv.y; n2 += wv * vv.z; n3 += wv * vv.w;
    }
    float* mo = Mc + ((size_t)(bh * NCH + c) * 64 + e) * 16 + g0;
    mo[0] = m0; mo[1] = m1; mo[2] = m2; mo[3] = m3;
    float* no = Nc + ((size_t)(bh * NCH + c) * 16 + g2) * 64 + e2;
    no[0] = n0; no[1] = n1; no[2] = n2; no[3] = n3;
}

// ---------------------------------------------------------------------------
// Merged scans.  bid < 512: inclusive cumsum nb over s of wbT (coalesced).
// bid >= 512: register-resident exclusive chunk-scan of Mc/Nc.
// ---------------------------------------------------------------------------
__global__ __launch_bounds__(256) void scans_kernel(const float* __restrict__ wbT,
                                                    float* __restrict__ nb,
                                                    float* __restrict__ Mc,
                                                    float* __restrict__ Nc) {
    const int bid = blockIdx.x;
    const int t = threadIdx.x;
    if (bid < NBH * NG) {
        __shared__ float sw[2048];
        __shared__ float sp[256];
#pragma unroll
        for (int p = 0; p < 2; ++p) {
            const int idx = (p * 256 + t) * 4;
            *(float4*)&sw[idx] = *(const float4*)&wbT[(size_t)bid * SL + idx];
        }
        __syncthreads();
        float loc[8];
        float run = 0.f;
#pragma unroll
        for (int j = 0; j < 8; ++j) { run += sw[t * 8 + j]; loc[j] = run; }
        sp[t] = run;
        __syncthreads();
        for (int off = 1; off < 256; off <<= 1) {
            const float v = sp[t];
            const float add = (t >= off) ? sp[t - off] : 0.f;
            __syncthreads();
            sp[t] = v + add;
            __syncthreads();
        }
        const float offs = (t > 0) ? sp[t - 1] : 0.f;
#pragma unroll
        for (int j = 0; j < 8; ++j)
            nb[(size_t)bid * SL + t * 8 + j] = offs + loc[j];
    } else {
        int gid = (bid - NBH * NG) * 256 + t;   // 0..65535 component id
        float* base;
        if (gid < NBH * 1024) base = Mc;
        else { base = Nc; gid -= NBH * 1024; }
        const int st = gid >> 10, comp = gid & 1023;
        float* p = base + (size_t)st * NCH * 1024 + comp;
        float v[NCH];
#pragma unroll
        for (int c = 0; c < NCH; ++c) v[c] = p[(size_t)c * 1024];
        float run = 0.f;
#pragma unroll
        for (int c = 0; c < NCH; ++c) {
            const float x = v[c];
            p[(size_t)c * 1024] = run;
            run += x;
        }
    }
}

// ---------------------------------------------------------------------------
// Fused pass1+pass2 (vectorized staging, 5 barriers, T14 V-load-early):
//   logits = causal(QK^T)@W + Q@P, /n, softmax -> Ct (LDS only)
//   out    = Ct@U + causal(Ct W^T)@V -> ohb (B,S,512) bf16
// grid (NBH, NCH).  LDS ~66.6 KB -> 2 blocks/CU.
// LDS reuse: Qs area -> Vt, Pt area -> Ut, At area -> St.
// ---------------------------------------------------------------------------
__global__ __launch_bounds__(256) void pass12_kernel(
    const ushort* __restrict__ qsb, const ushort* __restrict__ ksb,
    const float* __restrict__ wb, const float* __restrict__ nb,
    const float* __restrict__ Mc, const ushort* __restrict__ vsb,
    const float* __restrict__ Nc, ushort* __restrict__ ohb) {
    const int bh = blockIdx.x;
    const int b = bh >> 3, h = bh & 7;
    const int r = blockIdx.y;
    const int s0 = r * 64;
    __shared__ float Qs[64][65];    // later Vt (same padded layout)
    __shared__ float Kt[64][65];
    __shared__ float At[64][65];    // later St
    __shared__ float Wt[64 * 16];
    __shared__ float Pt[64 * 16];   // later Ut (16x64 linear)
    __shared__ float Lg[64][17];
    __shared__ float Ct[64][17];
    const int t = threadIdx.x;
    const int am = t >> 4, an = t & 15;
    const ushort* qbase = qsb + ((size_t)bh * SL + s0) * DH;
    const ushort* kbase = ksb + ((size_t)bh * SL + s0) * DH;
#pragma unroll
    for (int p = 0; p < 2; ++p) {
        const int idx = (p * 256 + t) * 8;
        const int row = idx >> 6, col = idx & 63;
        float4 lo, hi;
        unpack8(*(const bh8*)&qbase[idx], lo, hi);
        *(float4*)&Qs[row][col] = lo; *(float4*)&Qs[row][col + 4] = hi;
        unpack8(*(const bh8*)&kbase[idx], lo, hi);
        *(float4*)&Kt[row][col] = lo; *(float4*)&Kt[row][col + 4] = hi;
    }
    *(float4*)&Wt[t * 4] = *(const float4*)&wb[((size_t)bh * SL + s0) * NG + t * 4];
    *(float4*)&Pt[t * 4] = *(const float4*)&Mc[(size_t)(bh * NCH + r) * 1024 + t * 4];
    __syncthreads();                                   // (1) staging done
    // causal QK^T -> At
    float a[4][4] = {};
#pragma unroll 8
    for (int e = 0; e < 64; ++e) {
        float qv[4], kv[4];
#pragma unroll
        for (int j = 0; j < 4; ++j) qv[j] = Qs[am * 4 + j][e];
#pragma unroll
        for (int jj = 0; jj < 4; ++jj) kv[jj] = Kt[an * 4 + jj][e];
#pragma unroll
        for (int j = 0; j < 4; ++j)
#pragma unroll
            for (int jj = 0; jj < 4; ++jj) a[j][jj] += qv[j] * kv[jj];
    }
#pragma unroll
    for (int j = 0; j < 4; ++j)
#pragma unroll
        for (int jj = 0; jj < 4; ++jj) {
            if (an * 4 + jj > am * 4 + j) a[j][jj] = 0.f;
            At[am * 4 + j][an * 4 + jj] = a[j][jj];
        }
    __syncthreads();                                   // (2) At ready
    float lg[4] = {0.f, 0.f, 0.f, 0.f};
#pragma unroll 8
    for (int ii = 0; ii < 64; ++ii) {
        const float wv = Wt[ii * 16 + an];
#pragma unroll
        for (int j = 0; j < 4; ++j) lg[j] += At[am * 4 + j][ii] * wv;
    }
#pragma unroll 8
    for (int e = 0; e < 64; ++e) {
        const float pv = Pt[e * 16 + an];
#pragma unroll
        for (int j = 0; j < 4; ++j) lg[j] += Qs[am * 4 + j][e] * pv;
    }
#pragma unroll
    for (int j = 0; j < 4; ++j) Lg[am * 4 + j][an] = lg[j];
    __syncthreads();                                   // (3) Lg done; Qs/Pt/At free
    // T14: issue V + Nc loads FIRST (latency hides under softmax)
    const ushort* vbase = vsb + ((size_t)bh * SL + s0) * DH;
    const int vidx0 = t * 8, vidx1 = (256 + t) * 8;
    const bh8 v0 = *(const bh8*)&vbase[vidx0];
    const bh8 v1 = *(const bh8*)&vbase[vidx1];
    const float4 uu = *(const float4*)&Nc[(size_t)(bh * NCH + r) * 1024 + t * 4];
    // softmax (t < 64) -> Ct
    if (t < 64) {
        const int s = s0 + t;
        const float* nbase = nb + (size_t)bh * NG * SL + s;
        float nv[16], l[16];
        float mx = -1e30f;
#pragma unroll
        for (int g = 0; g < 16; ++g) {
            nv[g] = nbase[(size_t)g * SL];
            l[g] = Lg[t][g] / nv[g];
            mx = fmaxf(mx, l[g]);
        }
        float sum = 0.f;
#pragma unroll
        for (int g = 0; g < 16; ++g) { l[g] = expf(l[g] - mx); sum += l[g]; }
        const float inv = 1.f / sum;
#pragma unroll
        for (int g = 0; g < 16; ++g) Ct[t][g] = l[g] * inv / nv[g];
    }
    // write Vt into Qs area (padded rows), Ut into Pt area (linear)
    {
        float4 lo, hi;
        unpack8(v0, lo, hi);
        const int row0 = vidx0 >> 6, col0 = vidx0 & 63;
        *(float4*)&Qs[row0][col0] = lo; *(float4*)&Qs[row0][col0 + 4] = hi;
        unpack8(v1, lo, hi);
        const int row1 = vidx1 >> 6, col1 = vidx1 & 63;
        *(float4*)&Qs[row1][col1] = lo; *(float4*)&Qs[row1][col1 + 4] = hi;
        *(float4*)&Pt[t * 4] = uu;
    }
    __syncthreads();                                   // (4) Ct, Vt, Ut ready
    // S = causal(Ct @ Wt^T) -> St (At area)
    float sv[4][4] = {};
#pragma unroll
    for (int g = 0; g < 16; ++g) {
        float cv[4], wv[4];
#pragma unroll
        for (int j = 0; j < 4; ++j) cv[j] = Ct[am * 4 + j][g];
#pragma unroll
        for (int jj = 0; jj < 4; ++jj) wv[jj] = Wt[(an * 4 + jj) * 16 + g];
#pragma unroll
        for (int j = 0; j < 4; ++j)
#pragma unroll
            for (int jj = 0; jj < 4; ++jj) sv[j][jj] += cv[j] * wv[jj];
    }
#pragma unroll
    for (int j = 0; j < 4; ++j)
#pragma unroll
        for (int jj = 0; jj < 4; ++jj) {
            if (an * 4 + jj > am * 4 + j) sv[j][jj] = 0.f;
            At[am * 4 + j][an * 4 + jj] = sv[j][jj];
        }
    __syncthreads();                                   // (5) St ready
    float acc[4][4] = {};
#pragma unroll
    for (int g = 0; g < 16; ++g) {
        const float4 u = *(const float4*)&Pt[g * 64 + an * 4];
        float cv[4];
#pragma unroll
        for (int j = 0; j < 4; ++j) cv[j] = Ct[am * 4 + j][g];
#pragma unroll
        for (int j = 0; j < 4; ++j) {
            acc[j][0] += cv[j] * u.x; acc[j][1] += cv[j] * u.y;
            acc[j][2] += cv[j] * u.z; acc[j][3] += cv[j] * u.w;
        }
    }
#pragma unroll 8
    for (int ii = 0; ii < 64; ++ii) {
        const float4 vv = *(const float4*)&Qs[ii][an * 4];
        float st[4];
#pragma unroll
        for (int j = 0; j < 4; ++j) st[j] = At[am * 4 + j][ii];
#pragma unroll
        for (int j = 0; j < 4; ++j) {
            acc[j][0] += st[j] * vv.x; acc[j][1] += st[j] * vv.y;
            acc[j][2] += st[j] * vv.z; acc[j][3] += st[j] * vv.w;
        }
    }
#pragma unroll
    for (int j = 0; j < 4; ++j) {
        const int s = s0 + am * 4 + j;
        ushort4 pk;
        pk.x = f2bf(acc[j][0]); pk.y = f2bf(acc[j][1]);
        pk.z = f2bf(acc[j][2]); pk.w = f2bf(acc[j][3]);
        *(ushort4*)&ohb[((size_t)b * SL + s) * 512 + h * DH + an * 4] = pk;
    }
}

// ---------------------------------------------------------------------------
extern "C" void kernel_launch(void* const* d_in, const int* in_sizes, int n_in,
                              void* d_out, int out_size, void* d_ws, size_t ws_size,
                              hipStream_t stream) {
    const float* query   = (const float*)d_in[0];
    const float* key     = (const float*)d_in[1];
    const float* value   = (const float*)d_in[2];
    const float* context = (const float*)d_in[3];
    const float* qp = (const float*)d_in[4];
    const float* kp = (const float*)d_in[5];
    const float* vp = (const float*)d_in[6];
    const float* op = (const float*)d_in[7];
    const float* cp = (const float*)d_in[8];
    float* out = (float*)d_out;

    // ---- workspace layout (~61 MB, no aliasing) ----
    ushort* qsb = (ushort*)d_ws;            // 4,194,304 ushorts each
    ushort* ksb = qsb + 4194304;
    ushort* vsb = ksb + 4194304;
    ushort* ohb = vsb + 4194304;
    ushort* qpT = ohb + 4194304;            // 262,144 each
    ushort* kpT = qpT + 262144;
    ushort* vpT = kpT + 262144;
    ushort* opT = vpT + 262144;
    ushort* cpT = opT + 262144;             // 262,144
    ushort* ctxb = cpT + 262144;            // 32,768
    float* fbase = (float*)(ctxb + 32768);
    float* cs = fbase;                      // 32,768
    float* wb = cs + 32768;                 // 1,048,576 each
    float* nb = wb + 1048576;
    float* Mc = nb + 1048576;
    float* Nc = Mc + 1048576;
    float* wbT = Nc + 1048576;

    dim3 blk(256);
    prep_kernel<<<dim3(16, 16, 6), blk, 0, stream>>>(qp, kp, vp, op, cp, context,
                                                     qpT, kpT, vpT, opT, cpT, ctxb);
    gemm_ctx_kernel<<<dim3(4), blk, 0, stream>>>(ctxb, cpT, cs);
    gemm_qkv_kernel<<<dim3(128, 4, 3), blk, 0, stream>>>(query, key, value,
                                                         qpT, kpT, vpT, qsb, ksb, vsb);
    chunk_sums_w_kernel<<<dim3(NBH, NCH), blk, 0, stream>>>(ksb, vsb, cs, wb, wbT, Mc, Nc);
    scans_kernel<<<dim3(NBH * NG + 256), blk, 0, stream>>>(wbT, nb, Mc, Nc);
    pass12_kernel<<<dim3(NBH, NCH), blk, 0, stream>>>(qsb, ksb, wb, nb, Mc, vsb, Nc, ohb);
    gemm_out_kernel<<<dim3(128, 4), blk, 0, stream>>>(ohb, opT, out);
}

// Round 22
// 124.926 us; speedup vs baseline: 1.0584x; 1.0584x over previous
//
#include <hip/hip_runtime.h>
#include <hip/hip_bf16.h>

#define NB 4
#define SL 2048
#define NG 16
#define NH 8
#define DH 64
#define NBH (NB * NH)
#define NCH (SL / 64)  // 32 chunks of 64

typedef __attribute__((ext_vector_type(8))) short bh8;
typedef __attribute__((ext_vector_type(4))) float fx4;

__device__ __forceinline__ ushort f2bf(float x) {
    union { float f; unsigned u; } v; v.f = x;
    const unsigned r = v.u + 0x7fffu + ((v.u >> 16) & 1u);  // RNE
    return (ushort)(r >> 16);
}
__device__ __forceinline__ float b2f(ushort u) {
    union { unsigned u; float f; } v; v.u = ((unsigned)u) << 16;
    return v.f;
}
__device__ __forceinline__ bh8 pack8(float4 lo, float4 hi) {
    bh8 r;
    r[0] = (short)f2bf(lo.x); r[1] = (short)f2bf(lo.y);
    r[2] = (short)f2bf(lo.z); r[3] = (short)f2bf(lo.w);
    r[4] = (short)f2bf(hi.x); r[5] = (short)f2bf(hi.y);
    r[6] = (short)f2bf(hi.z); r[7] = (short)f2bf(hi.w);
    return r;
}
__device__ __forceinline__ void unpack8(bh8 v, float4& lo, float4& hi) {
    lo.x = b2f((ushort)v[0]); lo.y = b2f((ushort)v[1]);
    lo.z = b2f((ushort)v[2]); lo.w = b2f((ushort)v[3]);
    hi.x = b2f((ushort)v[4]); hi.y = b2f((ushort)v[5]);
    hi.z = b2f((ushort)v[6]); hi.w = b2f((ushort)v[7]);
}
// swizzle: within a 64-elem (128B) row, XOR elem bits 3..5 with row&7.
__device__ __forceinline__ int swz(int row, int col) {
    return row * 64 + (col ^ ((row & 7) << 3));
}

// ---------------------------------------------------------------------------
// prep: z<5 -> weight transpose f32->bf16 (tile 32x32), incl. cp.
//       z==5 -> context f32->bf16 (16 blocks).
// grid (16,16,6).
// ---------------------------------------------------------------------------
__global__ __launch_bounds__(256) void prep_kernel(
    const float* __restrict__ w0, const float* __restrict__ w1,
    const float* __restrict__ w2, const float* __restrict__ w3,
    const float* __restrict__ w4, const float* __restrict__ context,
    ushort* __restrict__ o0, ushort* __restrict__ o1,
    ushort* __restrict__ o2, ushort* __restrict__ o3,
    ushort* __restrict__ o4, ushort* __restrict__ ctxb) {
    const int z = blockIdx.z;
    const int t = threadIdx.x;
    if (z < 5) {
        const float* W = (z == 0) ? w0 : (z == 1) ? w1 : (z == 2) ? w2
                       : (z == 3) ? w3 : w4;
        ushort* WT = (z == 0) ? o0 : (z == 1) ? o1 : (z == 2) ? o2
                   : (z == 3) ? o3 : o4;
        __shared__ float tile[32][33];
        const int bx = blockIdx.x * 32, by = blockIdx.y * 32;
        const int tx = t & 31, ty = t >> 5;
#pragma unroll
        for (int p = 0; p < 4; ++p)
            tile[ty + p * 8][tx] = W[(size_t)(by + ty + p * 8) * 512 + bx + tx];
        __syncthreads();
#pragma unroll
        for (int p = 0; p < 4; ++p)
            WT[(size_t)(bx + ty + p * 8) * 512 + by + tx] = f2bf(tile[tx][ty + p * 8]);
    } else {
        if (blockIdx.x != 0 || blockIdx.y >= 16) return;
        const int idx = (blockIdx.y * 256 + t) * 8;  // 16*256*8 = 32768 elems
        const float4 lo = *(const float4*)&context[idx];
        const float4 hi = *(const float4*)&context[idx + 4];
        *(bh8*)&ctxb[idx] = pack8(lo, hi);
    }
}

// ---------------------------------------------------------------------------
// Context projection via MFMA: ctxb (64x512 bf16) @ cpT^T -> cs f32 heads.
// 64x128 tile, BK=64, swizzled LDS, counted-vmcnt pipeline.  grid (4).
// ---------------------------------------------------------------------------
__global__ __launch_bounds__(256) void gemm_ctx_kernel(const ushort* __restrict__ A,
                                                       const ushort* __restrict__ BT,
                                                       float* __restrict__ cs) {
    __shared__ __align__(16) ushort As[2][64 * 64];
    __shared__ __align__(16) ushort Bs[2][128 * 64];
    const int t = threadIdx.x;
    const int lane = t & 63, w = t >> 6;
    const int bn = blockIdx.x * 128;
    size_t asrc[2], bsrc[4];
#pragma unroll
    for (int i = 0; i < 2; ++i) {
        const int s = w * 1024 + i * 512 + lane * 8;
        const int r = s >> 6, o = (s & 63) ^ ((r & 7) << 3);
        asrc[i] = (size_t)r * 512 + o;
    }
#pragma unroll
    for (int i = 0; i < 4; ++i) {
        const int s = w * 2048 + i * 512 + lane * 8;
        const int r = s >> 6, o = (s & 63) ^ ((r & 7) << 3);
        bsrc[i] = (size_t)(bn + r) * 512 + o;
    }
    const int wr = w >> 1, wc = w & 1;
    const int fr = lane & 15, kg = lane >> 4;
    fx4 acc[2][4] = {};

#define STAGE_C(buf, kk)                                                       \
    do {                                                                       \
        _Pragma("unroll")                                                      \
        for (int i = 0; i < 2; ++i)                                            \
            __builtin_amdgcn_global_load_lds(                                  \
                (const __attribute__((address_space(1))) void*)(A + asrc[i] + (kk)), \
                (__attribute__((address_space(3))) void*)&As[buf][w * 1024 + i * 512], \
                16, 0, 0);                                                     \
        _Pragma("unroll")                                                      \
        for (int i = 0; i < 4; ++i)                                            \
            __builtin_amdgcn_global_load_lds(                                  \
                (const __attribute__((address_space(1))) void*)(BT + bsrc[i] + (kk)), \
                (__attribute__((address_space(3))) void*)&Bs[buf][w * 2048 + i * 512], \
                16, 0, 0);                                                     \
    } while (0)

    STAGE_C(0, 0);
    STAGE_C(1, 64);
    asm volatile("s_waitcnt vmcnt(6)" ::: "memory");
    __builtin_amdgcn_s_barrier();
    __builtin_amdgcn_sched_barrier(0);
    int cur = 0;
    for (int k0 = 0; k0 < 512; k0 += 64) {
#pragma unroll
        for (int kk = 0; kk < 2; ++kk) {
            bh8 af[2], bf[4];
#pragma unroll
            for (int m = 0; m < 2; ++m) {
                const int R = wr * 32 + m * 16 + fr;
                af[m] = *(const bh8*)&As[cur][swz(R, kk * 32 + kg * 8)];
            }
#pragma unroll
            for (int nn = 0; nn < 4; ++nn) {
                const int C = wc * 64 + nn * 16 + fr;
                bf[nn] = *(const bh8*)&Bs[cur][swz(C, kk * 32 + kg * 8)];
            }
#pragma unroll
            for (int m = 0; m < 2; ++m)
#pragma unroll
                for (int nn = 0; nn < 4; ++nn)
                    acc[m][nn] = __builtin_amdgcn_mfma_f32_16x16x32_bf16(
                        af[m], bf[nn], acc[m][nn], 0, 0, 0);
        }
        asm volatile("s_waitcnt lgkmcnt(0)" ::: "memory");
        __builtin_amdgcn_s_barrier();
        __builtin_amdgcn_sched_barrier(0);
        if (k0 + 128 < 512) {
            STAGE_C(cur, k0 + 128);
            asm volatile("s_waitcnt vmcnt(6)" ::: "memory");
        } else if (k0 + 64 < 512) {
            asm volatile("s_waitcnt vmcnt(0)" ::: "memory");
        }
        __builtin_amdgcn_sched_barrier(0);
        cur ^= 1;
    }
#undef STAGE_C
#pragma unroll
    for (int m = 0; m < 2; ++m)
#pragma unroll
        for (int nn = 0; nn < 4; ++nn)
#pragma unroll
            for (int j = 0; j < 4; ++j) {
                const int r = wr * 32 + m * 16 + kg * 4 + j;   // 0..63 = b*NG+i
                const int cc = bn + wc * 64 + nn * 16 + fr;
                const int b = r >> 4, i = r & 15;
                cs[(((size_t)(b * NH) + (cc >> 6)) * NG + i) * DH + (cc & 63)] =
                    acc[m][nn][j];
            }
}

// ---------------------------------------------------------------------------
// QKV MFMA GEMM, fused f32->bf16 of A.  64x128 tile, BK=64, swizzled LDS,
// raw-barrier + counted vmcnt + 2-deep A-register pipeline.  grid (128,4,3).
// NOTE: grid.x must stay ≡ 0 (mod 8): blocks sharing an A-panel (same x,
// different y) sit at linear stride grid.x; stride % 8 == 0 keeps them on
// one XCD so A re-reads hit L2 (R19: stride 129 -> FETCH 42->105 MB).
// ---------------------------------------------------------------------------
__global__ __launch_bounds__(256, 3) void gemm_qkv_kernel(
    const float* __restrict__ qf, const float* __restrict__ kf,
    const float* __restrict__ vf, const ushort* __restrict__ qpT,
    const ushort* __restrict__ kpT, const ushort* __restrict__ vpT,
    ushort* __restrict__ qsb, ushort* __restrict__ ksb, ushort* __restrict__ vsb) {
    const int z = blockIdx.z;
    const float* A32 = (z == 0) ? qf : (z == 1) ? kf : vf;
    const ushort* BT = (z == 0) ? qpT : (z == 1) ? kpT : vpT;
    ushort* out = (z == 0) ? qsb : (z == 1) ? ksb : vsb;

    __shared__ __align__(16) ushort As[2][64 * 64];
    __shared__ __align__(16) ushort Bs[2][128 * 64];
    const int t = threadIdx.x;
    const int lane = t & 63, w = t >> 6;
    const int bm = blockIdx.x * 64, bn = blockIdx.y * 128;
    const int ar = t >> 2, ao = (t & 3) * 16;
    const size_t abase = (size_t)(bm + ar) * 512 + ao;
    const int asw0 = swz(ar, ao), asw1 = swz(ar, ao + 8);
    size_t bsrc[4];
#pragma unroll
    for (int i = 0; i < 4; ++i) {
        const int s = w * 2048 + i * 512 + lane * 8;
        const int r = s >> 6, o = (s & 63) ^ ((r & 7) << 3);
        bsrc[i] = (size_t)(bn + r) * 512 + o;
    }
    const int wr = w >> 1, wc = w & 1;
    const int fr = lane & 15, kg = lane >> 4;
    fx4 acc[2][4] = {};
    float4 a00, a01, a02, a03;   // A register set 0
    float4 a10, a11, a12, a13;   // A register set 1

#define LOADA0(kk)                                                             \
    do {                                                                       \
        a00 = *(const float4*)&A32[abase + (kk)];                              \
        a01 = *(const float4*)&A32[abase + (kk) + 4];                          \
        a02 = *(const float4*)&A32[abase + (kk) + 8];                          \
        a03 = *(const float4*)&A32[abase + (kk) + 12];                         \
    } while (0)
#define LOADA1(kk)                                                             \
    do {                                                                       \
        a10 = *(const float4*)&A32[abase + (kk)];                              \
        a11 = *(const float4*)&A32[abase + (kk) + 4];                          \
        a12 = *(const float4*)&A32[abase + (kk) + 8];                          \
        a13 = *(const float4*)&A32[abase + (kk) + 12];                         \
    } while (0)
#define WRITEA0(buf)                                                           \
    do {                                                                       \
        *(bh8*)&As[buf][asw0] = pack8(a00, a01);                               \
        *(bh8*)&As[buf][asw1] = pack8(a02, a03);                               \
    } while (0)
#define WRITEA1(buf)                                                           \
    do {                                                                       \
        *(bh8*)&As[buf][asw0] = pack8(a10, a11);                               \
        *(bh8*)&As[buf][asw1] = pack8(a12, a13);                               \
    } while (0)
#define STAGEB(buf, kk)                                                        \
    do {                                                                       \
        _Pragma("unroll")                                                      \
        for (int i = 0; i < 4; ++i)                                            \
            __builtin_amdgcn_global_load_lds(                                  \
                (const __attribute__((address_space(1))) void*)(BT + bsrc[i] + (kk)), \
                (__attribute__((address_space(3))) void*)&Bs[buf][w * 2048 + i * 512], \
                16, 0, 0);                                                     \
    } while (0)
#define MFMA_PHASE(buf)                                                        \
    do {                                                                       \
        _Pragma("unroll")                                                      \
        for (int kk = 0; kk < 2; ++kk) {                                       \
            bh8 af[2], bf[4];                                                  \
            _Pragma("unroll")                                                  \
            for (int m = 0; m < 2; ++m) {                                      \
                const int R = wr * 32 + m * 16 + fr;                           \
                af[m] = *(const bh8*)&As[buf][swz(R, kk * 32 + kg * 8)];       \
            }                                                                  \
            _Pragma("unroll")                                                  \
            for (int nn = 0; nn < 4; ++nn) {                                   \
                const int C = wc * 64 + nn * 16 + fr;                          \
                bf[nn] = *(const bh8*)&Bs[buf][swz(C, kk * 32 + kg * 8)];      \
            }                                                                  \
            _Pragma("unroll")                                                  \
            for (int m = 0; m < 2; ++m)                                        \
                _Pragma("unroll")                                              \
                for (int nn = 0; nn < 4; ++nn)                                 \
                    acc[m][nn] = __builtin_amdgcn_mfma_f32_16x16x32_bf16(      \
                        af[m], bf[nn], acc[m][nn], 0, 0, 0);                   \
        }                                                                      \
    } while (0)

    // prologue: buf0 fully staged; B(64) in flight; A(64)->set1, A(128)->set0
    STAGEB(0, 0);
    LOADA0(0);
    WRITEA0(0);                      // compiler drains A(0) loads
    LOADA1(64);
    LOADA0(128);
    STAGEB(1, 64);
    asm volatile("s_waitcnt vmcnt(12) lgkmcnt(0)" ::: "memory");  // B(0) done
    __builtin_amdgcn_s_barrier();
    __builtin_amdgcn_sched_barrier(0);

#pragma unroll
    for (int p = 0; p < 8; ++p) {
        const int k0 = p * 64;
        const int buf = p & 1;
        MFMA_PHASE(buf);
        if (p < 7) {                 // pack A(k0+64), loaded TWO phases ago
            if (((p + 1) & 1) == 0) WRITEA0(buf ^ 1);
            else                    WRITEA1(buf ^ 1);
        }
        asm volatile("s_waitcnt lgkmcnt(0)" ::: "memory");
        __builtin_amdgcn_s_barrier();
        __builtin_amdgcn_sched_barrier(0);
        if (p <= 5) STAGEB(buf, k0 + 128);   // restage buffer just read
        if (p <= 4) {                        // A(k0+192) into freed set
            if (((p + 1) & 1) == 0) LOADA0(k0 + 192);
            else                    LOADA1(k0 + 192);
        }
        if (p <= 4)      asm volatile("s_waitcnt vmcnt(12)" ::: "memory");
        else if (p == 5) asm volatile("s_waitcnt vmcnt(8)" ::: "memory");
        else if (p == 6) asm volatile("s_waitcnt vmcnt(0)" ::: "memory");
        __builtin_amdgcn_sched_barrier(0);
    }
#undef LOADA0
#undef LOADA1
#undef WRITEA0
#undef WRITEA1
#undef STAGEB
#undef MFMA_PHASE
#pragma unroll
    for (int m = 0; m < 2; ++m)
#pragma unroll
        for (int nn = 0; nn < 4; ++nn)
#pragma unroll
            for (int j = 0; j < 4; ++j) {
                const int r = bm + wr * 32 + m * 16 + kg * 4 + j;
                const int cc = bn + wc * 64 + nn * 16 + fr;
                const int b = r >> 11, i = r & 2047;  // SL = 2048
                out[(((size_t)(b * NH) + (cc >> 6)) * SL + i) * DH + (cc & 63)] =
                    f2bf(acc[m][nn][j]);
            }
}

// ---------------------------------------------------------------------------
// Output MFMA GEMM: ohb (8192x512 bf16) @ opT^T -> f32 plain.
// 64x128 tile, BK=64, swizzled LDS, counted-vmcnt pipeline.  grid (128,4).
// ---------------------------------------------------------------------------
__global__ __launch_bounds__(256, 3) void gemm_out_kernel(const ushort* __restrict__ A,
                                                          const ushort* __restrict__ BT,
                                                          float* __restrict__ out) {
    __shared__ __align__(16) ushort As[2][64 * 64];
    __shared__ __align__(16) ushort Bs[2][128 * 64];
    const int t = threadIdx.x;
    const int lane = t & 63, w = t >> 6;
    const int bm = blockIdx.x * 64, bn = blockIdx.y * 128;
    size_t asrc[2], bsrc[4];
#pragma unroll
    for (int i = 0; i < 2; ++i) {
        const int s = w * 1024 + i * 512 + lane * 8;
        const int r = s >> 6, o = (s & 63) ^ ((r & 7) << 3);
        asrc[i] = (size_t)(bm + r) * 512 + o;
    }
#pragma unroll
    for (int i = 0; i < 4; ++i) {
        const int s = w * 2048 + i * 512 + lane * 8;
        const int r = s >> 6, o = (s & 63) ^ ((r & 7) << 3);
        bsrc[i] = (size_t)(bn + r) * 512 + o;
    }
    const int wr = w >> 1, wc = w & 1;
    const int fr = lane & 15, kg = lane >> 4;
    fx4 acc[2][4] = {};

#define STAGE_O(buf, kk)                                                       \
    do {                                                                       \
        _Pragma("unroll")                                                      \
        for (int i = 0; i < 2; ++i)                                            \
            __builtin_amdgcn_global_load_lds(                                  \
                (const __attribute__((address_space(1))) void*)(A + asrc[i] + (kk)), \
                (__attribute__((address_space(3))) void*)&As[buf][w * 1024 + i * 512], \
                16, 0, 0);                                                     \
        _Pragma("unroll")                                                      \
        for (int i = 0; i < 4; ++i)                                            \
            __builtin_amdgcn_global_load_lds(                                  \
                (const __attribute__((address_space(1))) void*)(BT + bsrc[i] + (kk)), \
                (__attribute__((address_space(3))) void*)&Bs[buf][w * 2048 + i * 512], \
                16, 0, 0);                                                     \
    } while (0)

    STAGE_O(0, 0);
    STAGE_O(1, 64);
    asm volatile("s_waitcnt vmcnt(6)" ::: "memory");  // buf0's 6 ops done
    __builtin_amdgcn_s_barrier();
    __builtin_amdgcn_sched_barrier(0);
    int cur = 0;
    for (int k0 = 0; k0 < 512; k0 += 64) {
#pragma unroll
        for (int kk = 0; kk < 2; ++kk) {
            bh8 af[2], bf[4];
#pragma unroll
            for (int m = 0; m < 2; ++m) {
                const int R = wr * 32 + m * 16 + fr;
                af[m] = *(const bh8*)&As[cur][swz(R, kk * 32 + kg * 8)];
            }
#pragma unroll
            for (int nn = 0; nn < 4; ++nn) {
                const int C = wc * 64 + nn * 16 + fr;
                bf[nn] = *(const bh8*)&Bs[cur][swz(C, kk * 32 + kg * 8)];
            }
#pragma unroll
            for (int m = 0; m < 2; ++m)
#pragma unroll
                for (int nn = 0; nn < 4; ++nn)
                    acc[m][nn] = __builtin_amdgcn_mfma_f32_16x16x32_bf16(
                        af[m], bf[nn], acc[m][nn], 0, 0, 0);
        }
        asm volatile("s_waitcnt lgkmcnt(0)" ::: "memory");
        __builtin_amdgcn_s_barrier();
        __builtin_amdgcn_sched_barrier(0);
        if (k0 + 128 < 512) {
            STAGE_O(cur, k0 + 128);
            asm volatile("s_waitcnt vmcnt(6)" ::: "memory");
        } else if (k0 + 64 < 512) {
            asm volatile("s_waitcnt vmcnt(0)" ::: "memory");
        }
        __builtin_amdgcn_sched_barrier(0);
        cur ^= 1;
    }
#undef STAGE_O
#pragma unroll
    for (int m = 0; m < 2; ++m)
#pragma unroll
        for (int nn = 0; nn < 4; ++nn)
#pragma unroll
            for (int j = 0; j < 4; ++j) {
                const int r = bm + wr * 32 + m * 16 + kg * 4 + j;
                const int cc = bn + wc * 64 + nn * 16 + fr;
                out[(size_t)r * 512 + cc] = acc[m][nn][j];
            }
}

// ---------------------------------------------------------------------------
// Fused: W = exp(Ks@Cs^T) -> wb (s,g) + wbT (g,s) + per-chunk sums M_c, N_c.
// grid (NBH, NCH).
// ---------------------------------------------------------------------------
__global__ __launch_bounds__(256) void chunk_sums_w_kernel(
    const ushort* __restrict__ ksb, const ushort* __restrict__ vsb,
    const float* __restrict__ cs, float* __restrict__ wb,
    float* __restrict__ wbT, float* __restrict__ Mc, float* __restrict__ Nc) {
    const int bh = blockIdx.x, c = blockIdx.y;
    __shared__ float Ks[64 * 64];
    __shared__ float Vs[64 * 64];
    __shared__ float Ws[64 * 16];
    __shared__ float Cs[16][65];
    const int t = threadIdx.x;
    const ushort* kbase = ksb + ((size_t)bh * SL + c * 64) * DH;
    const ushort* vbase = vsb + ((size_t)bh * SL + c * 64) * DH;
#pragma unroll
    for (int p = 0; p < 2; ++p) {
        const int idx = (p * 256 + t) * 8;
        float4 lo, hi;
        unpack8(*(const bh8*)&kbase[idx], lo, hi);
        *(float4*)&Ks[idx] = lo; *(float4*)&Ks[idx + 4] = hi;
        unpack8(*(const bh8*)&vbase[idx], lo, hi);
        *(float4*)&Vs[idx] = lo; *(float4*)&Vs[idx + 4] = hi;
    }
    {
        const int idx = t * 4;
        const float4 cv = *(const float4*)&cs[(size_t)bh * NG * DH + idx];
        const int g = idx >> 6, e = idx & 63;
        Cs[g][e + 0] = cv.x; Cs[g][e + 1] = cv.y; Cs[g][e + 2] = cv.z; Cs[g][e + 3] = cv.w;
    }
    __syncthreads();
    {
        const int i = (t * 4) >> 4, g0 = (t * 4) & 15;
        float d0 = 0.f, d1 = 0.f, d2 = 0.f, d3 = 0.f;
#pragma unroll 8
        for (int e = 0; e < 64; ++e) {
            const float kv = Ks[i * 64 + e];
            d0 += kv * Cs[g0 + 0][e];
            d1 += kv * Cs[g0 + 1][e];
            d2 += kv * Cs[g0 + 2][e];
            d3 += kv * Cs[g0 + 3][e];
        }
        float4 wv;
        wv.x = expf(d0); wv.y = expf(d1); wv.z = expf(d2); wv.w = expf(d3);
        *(float4*)&Ws[i * 16 + g0] = wv;
        *(float4*)&wb[((size_t)bh * SL + c * 64 + i) * NG + g0] = wv;
    }
    __syncthreads();
    {
        const int g = t >> 4, i0 = (t & 15) * 4;
        float4 wv4;
        wv4.x = Ws[(i0 + 0) * 16 + g];
        wv4.y = Ws[(i0 + 1) * 16 + g];
        wv4.z = Ws[(i0 + 2) * 16 + g];
        wv4.w = Ws[(i0 + 3) * 16 + g];
        *(float4*)&wbT[((size_t)(bh * NG) + g) * SL + c * 64 + i0] = wv4;
    }
    const int e = t >> 2, g0 = (t & 3) * 4;
    float m0 = 0.f, m1 = 0.f, m2 = 0.f, m3 = 0.f;
#pragma unroll 8
    for (int i = 0; i < 64; ++i) {
        const float kv = Ks[i * 64 + e];
        const float4 w = *(const float4*)&Ws[i * 16 + g0];
        m0 += kv * w.x; m1 += kv * w.y; m2 += kv * w.z; m3 += kv * w.w;
    }
    const int g2 = t >> 4, e2 = (t & 15) * 4;
    float n0 = 0.f, n1 = 0.f, n2 = 0.f, n3 = 0.f;
#pragma unroll 8
    for (int i = 0; i < 64; ++i) {
        const float wv = Ws[i * 16 + g2];
        const float4 vv = *(const float4*)&Vs[i * 64 + e2];
        n0 += wv * vv.x; n1 += wv * vv.y; n2 += wv * vv.z; n3 += wv * vv.w;
    }
    float* mo = Mc + ((size_t)(bh * NCH + c) * 64 + e) * 16 + g0;
    mo[0] = m0; mo[1] = m1; mo[2] = m2; mo[3] = m3;
    float* no = Nc + ((size_t)(bh * NCH + c) * 16 + g2) * 64 + e2;
    no[0] = n0; no[1] = n1; no[2] = n2; no[3] = n3;
}

// ---------------------------------------------------------------------------
// Merged scans.  bid < 512: inclusive cumsum nb over s of wbT (coalesced).
// bid >= 512: register-resident exclusive chunk-scan of Mc/Nc.
// ---------------------------------------------------------------------------
__global__ __launch_bounds__(256) void scans_kernel(const float* __restrict__ wbT,
                                                    float* __restrict__ nb,
                                                    float* __restrict__ Mc,
                                                    float* __restrict__ Nc) {
    const int bid = blockIdx.x;
    const int t = threadIdx.x;
    if (bid < NBH * NG) {
        __shared__ float sw[2048];
        __shared__ float sp[256];
#pragma unroll
        for (int p = 0; p < 2; ++p) {
            const int idx = (p * 256 + t) * 4;
            *(float4*)&sw[idx] = *(const float4*)&wbT[(size_t)bid * SL + idx];
        }
        __syncthreads();
        float loc[8];
        float run = 0.f;
#pragma unroll
        for (int j = 0; j < 8; ++j) { run += sw[t * 8 + j]; loc[j] = run; }
        sp[t] = run;
        __syncthreads();
        for (int off = 1; off < 256; off <<= 1) {
            const float v = sp[t];
            const float add = (t >= off) ? sp[t - off] : 0.f;
            __syncthreads();
            sp[t] = v + add;
            __syncthreads();
        }
        const float offs = (t > 0) ? sp[t - 1] : 0.f;
#pragma unroll
        for (int j = 0; j < 8; ++j)
            nb[(size_t)bid * SL + t * 8 + j] = offs + loc[j];
    } else {
        int gid = (bid - NBH * NG) * 256 + t;   // 0..65535 component id
        float* base;
        if (gid < NBH * 1024) base = Mc;
        else { base = Nc; gid -= NBH * 1024; }
        const int st = gid >> 10, comp = gid & 1023;
        float* p = base + (size_t)st * NCH * 1024 + comp;
        float v[NCH];
#pragma unroll
        for (int c = 0; c < NCH; ++c) v[c] = p[(size_t)c * 1024];
        float run = 0.f;
#pragma unroll
        for (int c = 0; c < NCH; ++c) {
            const float x = v[c];
            p[(size_t)c * 1024] = run;
            run += x;
        }
    }
}

// ---------------------------------------------------------------------------
// pass1c: logits = causal(QK^T)@W + Q@P, /n, softmax over g, c = p/(sum*n)
// grid (NBH, NCH).
// ---------------------------------------------------------------------------
__global__ __launch_bounds__(256) void pass1c_kernel(const ushort* __restrict__ qsb,
                                                     const ushort* __restrict__ ksb,
                                                     const float* __restrict__ wb,
                                                     const float* __restrict__ nb,
                                                     const float* __restrict__ Mc,
                                                     float* __restrict__ cb) {
    const int bh = blockIdx.x;
    const int r = blockIdx.y;
    const int s0 = r * 64;
    __shared__ float Qs[64][65];
    __shared__ float Kt[64][65];
    __shared__ float At[64][65];
    __shared__ float Wt[64 * 16];
    __shared__ float Pt[64 * 16];
    __shared__ float Lg[64][17];
    const int t = threadIdx.x;
    const int am = t >> 4, an = t & 15;
    const ushort* qbase = qsb + ((size_t)bh * SL + s0) * DH;
    const ushort* kbase = ksb + ((size_t)bh * SL + s0) * DH;
#pragma unroll
    for (int p = 0; p < 2; ++p) {
        const int idx = (p * 256 + t) * 8;
        const int row = idx >> 6, col = idx & 63;
        float4 lo, hi;
        unpack8(*(const bh8*)&qbase[idx], lo, hi);
        *(float4*)&Qs[row][col] = lo; *(float4*)&Qs[row][col + 4] = hi;
        unpack8(*(const bh8*)&kbase[idx], lo, hi);
        *(float4*)&Kt[row][col] = lo; *(float4*)&Kt[row][col + 4] = hi;
    }
    *(float4*)&Wt[t * 4] = *(const float4*)&wb[((size_t)bh * SL + s0) * NG + t * 4];
    *(float4*)&Pt[t * 4] = *(const float4*)&Mc[(size_t)(bh * NCH + r) * 1024 + t * 4];
    __syncthreads();
    float a[4][4] = {};
#pragma unroll 8
    for (int e = 0; e < 64; ++e) {
        float qv[4], kv[4];
#pragma unroll
        for (int j = 0; j < 4; ++j) qv[j] = Qs[am * 4 + j][e];
#pragma unroll
        for (int jj = 0; jj < 4; ++jj) kv[jj] = Kt[an * 4 + jj][e];
#pragma unroll
        for (int j = 0; j < 4; ++j)
#pragma unroll
            for (int jj = 0; jj < 4; ++jj) a[j][jj] += qv[j] * kv[jj];
    }
#pragma unroll
    for (int j = 0; j < 4; ++j)
#pragma unroll
        for (int jj = 0; jj < 4; ++jj) {
            if (an * 4 + jj > am * 4 + j) a[j][jj] = 0.f;
            At[am * 4 + j][an * 4 + jj] = a[j][jj];
        }
    __syncthreads();
    float lg[4] = {0.f, 0.f, 0.f, 0.f};
#pragma unroll 8
    for (int ii = 0; ii < 64; ++ii) {
        const float wv = Wt[ii * 16 + an];
#pragma unroll
        for (int j = 0; j < 4; ++j) lg[j] += At[am * 4 + j][ii] * wv;
    }
#pragma unroll 8
    for (int e = 0; e < 64; ++e) {
        const float pv = Pt[e * 16 + an];
#pragma unroll
        for (int j = 0; j < 4; ++j) lg[j] += Qs[am * 4 + j][e] * pv;
    }
#pragma unroll
    for (int j = 0; j < 4; ++j) Lg[am * 4 + j][an] = lg[j];
    __syncthreads();
    if (t < 64) {
        const int s = s0 + t;
        const float* nbase = nb + (size_t)bh * NG * SL + s;
        float nv[16], l[16];
        float mx = -1e30f;
#pragma unroll
        for (int g = 0; g < 16; ++g) {
            nv[g] = nbase[(size_t)g * SL];
            l[g] = Lg[t][g] / nv[g];
            mx = fmaxf(mx, l[g]);
        }
        float sum = 0.f;
#pragma unroll
        for (int g = 0; g < 16; ++g) { l[g] = expf(l[g] - mx); sum += l[g]; }
        const float inv = 1.f / sum;
#pragma unroll
        for (int g = 0; g < 16; ++g)
            cb[((size_t)bh * SL + s) * NG + g] = l[g] * inv / nv[g];
    }
}

// ---------------------------------------------------------------------------
// pass2c: out = C@U + causal(C W^T)@V  -> ohb (B,S,512) bf16
// grid (NBH, NCH).
// ---------------------------------------------------------------------------
__global__ __launch_bounds__(256) void pass2c_kernel(const float* __restrict__ cb,
                                                     const float* __restrict__ wb,
                                                     const ushort* __restrict__ vsb,
                                                     const float* __restrict__ Nc,
                                                     ushort* __restrict__ ohb) {
    const int bh = blockIdx.x;
    const int b = bh >> 3, h = bh & 7;
    const int r = blockIdx.y;
    const int s0 = r * 64;
    __shared__ float Ct[64][17];
    __shared__ float Wt[64][17];
    __shared__ float Vt[64 * 64];
    __shared__ float St[64][65];
    __shared__ float Ut[16 * 64];
    const int t = threadIdx.x;
    const int am = t >> 4, an = t & 15;
    {
        const int idx = t * 4;
        const int row = idx >> 4, g0 = idx & 15;
        const float4 cv = *(const float4*)&cb[((size_t)bh * SL + s0) * NG + idx];
        Ct[row][g0 + 0] = cv.x; Ct[row][g0 + 1] = cv.y;
        Ct[row][g0 + 2] = cv.z; Ct[row][g0 + 3] = cv.w;
        const float4 wv = *(const float4*)&wb[((size_t)bh * SL + s0) * NG + idx];
        Wt[row][g0 + 0] = wv.x; Wt[row][g0 + 1] = wv.y;
        Wt[row][g0 + 2] = wv.z; Wt[row][g0 + 3] = wv.w;
    }
    const ushort* vbase = vsb + ((size_t)bh * SL + s0) * DH;
#pragma unroll
    for (int p = 0; p < 2; ++p) {
        const int idx = (p * 256 + t) * 8;
        float4 lo, hi;
        unpack8(*(const bh8*)&vbase[idx], lo, hi);
        *(float4*)&Vt[idx] = lo; *(float4*)&Vt[idx + 4] = hi;
    }
    *(float4*)&Ut[t * 4] = *(const float4*)&Nc[(size_t)(bh * NCH + r) * 1024 + t * 4];
    __syncthreads();
    float sv[4][4] = {};
#pragma unroll
    for (int g = 0; g < 16; ++g) {
        float cv[4], wv[4];
#pragma unroll
        for (int j = 0; j < 4; ++j) cv[j] = Ct[am * 4 + j][g];
#pragma unroll
        for (int jj = 0; jj < 4; ++jj) wv[jj] = Wt[an * 4 + jj][g];
#pragma unroll
        for (int j = 0; j < 4; ++j)
#pragma unroll
            for (int jj = 0; jj < 4; ++jj) sv[j][jj] += cv[j] * wv[jj];
    }
#pragma unroll
    for (int j = 0; j < 4; ++j)
#pragma unroll
        for (int jj = 0; jj < 4; ++jj) {
            if (an * 4 + jj > am * 4 + j) sv[j][jj] = 0.f;
            St[am * 4 + j][an * 4 + jj] = sv[j][jj];
        }
    __syncthreads();
    float acc[4][4] = {};
#pragma unroll
    for (int g = 0; g < 16; ++g) {
        const float4 u = *(const float4*)&Ut[g * 64 + an * 4];
        float cv[4];
#pragma unroll
        for (int j = 0; j < 4; ++j) cv[j] = Ct[am * 4 + j][g];
#pragma unroll
        for (int j = 0; j < 4; ++j) {
            acc[j][0] += cv[j] * u.x; acc[j][1] += cv[j] * u.y;
            acc[j][2] += cv[j] * u.z; acc[j][3] += cv[j] * u.w;
        }
    }
#pragma unroll 8
    for (int ii = 0; ii < 64; ++ii) {
        const float4 vv = *(const float4*)&Vt[ii * 64 + an * 4];
        float st[4];
#pragma unroll
        for (int j = 0; j < 4; ++j) st[j] = St[am * 4 + j][ii];
#pragma unroll
        for (int j = 0; j < 4; ++j) {
            acc[j][0] += st[j] * vv.x; acc[j][1] += st[j] * vv.y;
            acc[j][2] += st[j] * vv.z; acc[j][3] += st[j] * vv.w;
        }
    }
#pragma unroll
    for (int j = 0; j < 4; ++j) {
        const int s = s0 + am * 4 + j;
        ushort4 pk;
        pk.x = f2bf(acc[j][0]); pk.y = f2bf(acc[j][1]);
        pk.z = f2bf(acc[j][2]); pk.w = f2bf(acc[j][3]);
        *(ushort4*)&ohb[((size_t)b * SL + s) * 512 + h * DH + an * 4] = pk;
    }
}

// ---------------------------------------------------------------------------
extern "C" void kernel_launch(void* const* d_in, const int* in_sizes, int n_in,
                              void* d_out, int out_size, void* d_ws, size_t ws_size,
                              hipStream_t stream) {
    const float* query   = (const float*)d_in[0];
    const float* key     = (const float*)d_in[1];
    const float* value   = (const float*)d_in[2];
    const float* context = (const float*)d_in[3];
    const float* qp = (const float*)d_in[4];
    const float* kp = (const float*)d_in[5];
    const float* vp = (const float*)d_in[6];
    const float* op = (const float*)d_in[7];
    const float* cp = (const float*)d_in[8];
    float* out = (float*)d_out;

    // ---- workspace layout (~61 MB, no aliasing) ----
    ushort* qsb = (ushort*)d_ws;            // 4,194,304 ushorts each
    ushort* ksb = qsb + 4194304;
    ushort* vsb = ksb + 4194304;
    ushort* ohb = vsb + 4194304;
    ushort* qpT = ohb + 4194304;            // 262,144 each
    ushort* kpT = qpT + 262144;
    ushort* vpT = kpT + 262144;
    ushort* opT = vpT + 262144;
    ushort* cpT = opT + 262144;             // 262,144
    ushort* ctxb = cpT + 262144;            // 32,768
    float* fbase = (float*)(ctxb + 32768);
    float* cs = fbase;                      // 32,768
    float* wb = cs + 32768;                 // 1,048,576 each
    float* nb = wb + 1048576;
    float* Mc = nb + 1048576;
    float* Nc = Mc + 1048576;
    float* cb = Nc + 1048576;
    float* wbT = cb + 1048576;

    dim3 blk(256);
    prep_kernel<<<dim3(16, 16, 6), blk, 0, stream>>>(qp, kp, vp, op, cp, context,
                                                     qpT, kpT, vpT, opT, cpT, ctxb);
    gemm_ctx_kernel<<<dim3(4), blk, 0, stream>>>(ctxb, cpT, cs);
    gemm_qkv_kernel<<<dim3(128, 4, 3), blk, 0, stream>>>(query, key, value,
                                                         qpT, kpT, vpT, qsb, ksb, vsb);
    chunk_sums_w_kernel<<<dim3(NBH, NCH), blk, 0, stream>>>(ksb, vsb, cs, wb, wbT, Mc, Nc);
    scans_kernel<<<dim3(NBH * NG + 256), blk, 0, stream>>>(wbT, nb, Mc, Nc);
    pass1c_kernel<<<dim3(NBH, NCH), blk, 0, stream>>>(qsb, ksb, wb, nb, Mc, cb);
    pass2c_kernel<<<dim3(NBH, NCH), blk, 0, stream>>>(cb, wb, vsb, Nc, ohb);
    gemm_out_kernel<<<dim3(128, 4), blk, 0, stream>>>(ohb, opT, out);
}

// Round 23
// 124.566 us; speedup vs baseline: 1.0615x; 1.0029x over previous
//
#include <hip/hip_runtime.h>
#include <hip/hip_bf16.h>

#define NB 4
#define SL 2048
#define NG 16
#define NH 8
#define DH 64
#define NBH (NB * NH)
#define NCH (SL / 64)  // 32 chunks of 64

typedef __attribute__((ext_vector_type(8))) short bh8;
typedef __attribute__((ext_vector_type(4))) float fx4;

__device__ __forceinline__ ushort f2bf(float x) {
    union { float f; unsigned u; } v; v.f = x;
    const unsigned r = v.u + 0x7fffu + ((v.u >> 16) & 1u);  // RNE
    return (ushort)(r >> 16);
}
__device__ __forceinline__ float b2f(ushort u) {
    union { unsigned u; float f; } v; v.u = ((unsigned)u) << 16;
    return v.f;
}
__device__ __forceinline__ bh8 pack8(float4 lo, float4 hi) {
    bh8 r;
    r[0] = (short)f2bf(lo.x); r[1] = (short)f2bf(lo.y);
    r[2] = (short)f2bf(lo.z); r[3] = (short)f2bf(lo.w);
    r[4] = (short)f2bf(hi.x); r[5] = (short)f2bf(hi.y);
    r[6] = (short)f2bf(hi.z); r[7] = (short)f2bf(hi.w);
    return r;
}
__device__ __forceinline__ void unpack8(bh8 v, float4& lo, float4& hi) {
    lo.x = b2f((ushort)v[0]); lo.y = b2f((ushort)v[1]);
    lo.z = b2f((ushort)v[2]); lo.w = b2f((ushort)v[3]);
    hi.x = b2f((ushort)v[4]); hi.y = b2f((ushort)v[5]);
    hi.z = b2f((ushort)v[6]); hi.w = b2f((ushort)v[7]);
}
// swizzle: within a 64-elem (128B) row, XOR elem bits 3..5 with row&7.
__device__ __forceinline__ int swz(int row, int col) {
    return row * 64 + (col ^ ((row & 7) << 3));
}

// ---------------------------------------------------------------------------
// prep: z<5 -> weight transpose f32->bf16 (tile 32x32), incl. cp.
//       z==5 -> context f32->bf16 (16 blocks).
// grid (16,16,6).
// ---------------------------------------------------------------------------
__global__ __launch_bounds__(256) void prep_kernel(
    const float* __restrict__ w0, const float* __restrict__ w1,
    const float* __restrict__ w2, const float* __restrict__ w3,
    const float* __restrict__ w4, const float* __restrict__ context,
    ushort* __restrict__ o0, ushort* __restrict__ o1,
    ushort* __restrict__ o2, ushort* __restrict__ o3,
    ushort* __restrict__ o4, ushort* __restrict__ ctxb) {
    const int z = blockIdx.z;
    const int t = threadIdx.x;
    if (z < 5) {
        const float* W = (z == 0) ? w0 : (z == 1) ? w1 : (z == 2) ? w2
                       : (z == 3) ? w3 : w4;
        ushort* WT = (z == 0) ? o0 : (z == 1) ? o1 : (z == 2) ? o2
                   : (z == 3) ? o3 : o4;
        __shared__ float tile[32][33];
        const int bx = blockIdx.x * 32, by = blockIdx.y * 32;
        const int tx = t & 31, ty = t >> 5;
#pragma unroll
        for (int p = 0; p < 4; ++p)
            tile[ty + p * 8][tx] = W[(size_t)(by + ty + p * 8) * 512 + bx + tx];
        __syncthreads();
#pragma unroll
        for (int p = 0; p < 4; ++p)
            WT[(size_t)(bx + ty + p * 8) * 512 + by + tx] = f2bf(tile[tx][ty + p * 8]);
    } else {
        if (blockIdx.x != 0 || blockIdx.y >= 16) return;
        const int idx = (blockIdx.y * 256 + t) * 8;  // 16*256*8 = 32768 elems
        const float4 lo = *(const float4*)&context[idx];
        const float4 hi = *(const float4*)&context[idx + 4];
        *(bh8*)&ctxb[idx] = pack8(lo, hi);
    }
}

// ---------------------------------------------------------------------------
// Context projection via MFMA: ctxb (64x512 bf16) @ cpT^T -> cs f32 heads.
// 64x128 tile, BK=64, swizzled LDS, counted-vmcnt pipeline.  grid (4).
// ---------------------------------------------------------------------------
__global__ __launch_bounds__(256) void gemm_ctx_kernel(const ushort* __restrict__ A,
                                                       const ushort* __restrict__ BT,
                                                       float* __restrict__ cs) {
    __shared__ __align__(16) ushort As[2][64 * 64];
    __shared__ __align__(16) ushort Bs[2][128 * 64];
    const int t = threadIdx.x;
    const int lane = t & 63, w = t >> 6;
    const int bn = blockIdx.x * 128;
    size_t asrc[2], bsrc[4];
#pragma unroll
    for (int i = 0; i < 2; ++i) {
        const int s = w * 1024 + i * 512 + lane * 8;
        const int r = s >> 6, o = (s & 63) ^ ((r & 7) << 3);
        asrc[i] = (size_t)r * 512 + o;
    }
#pragma unroll
    for (int i = 0; i < 4; ++i) {
        const int s = w * 2048 + i * 512 + lane * 8;
        const int r = s >> 6, o = (s & 63) ^ ((r & 7) << 3);
        bsrc[i] = (size_t)(bn + r) * 512 + o;
    }
    const int wr = w >> 1, wc = w & 1;
    const int fr = lane & 15, kg = lane >> 4;
    fx4 acc[2][4] = {};

#define STAGE_C(buf, kk)                                                       \
    do {                                                                       \
        _Pragma("unroll")                                                      \
        for (int i = 0; i < 2; ++i)                                            \
            __builtin_amdgcn_global_load_lds(                                  \
                (const __attribute__((address_space(1))) void*)(A + asrc[i] + (kk)), \
                (__attribute__((address_space(3))) void*)&As[buf][w * 1024 + i * 512], \
                16, 0, 0);                                                     \
        _Pragma("unroll")                                                      \
        for (int i = 0; i < 4; ++i)                                            \
            __builtin_amdgcn_global_load_lds(                                  \
                (const __attribute__((address_space(1))) void*)(BT + bsrc[i] + (kk)), \
                (__attribute__((address_space(3))) void*)&Bs[buf][w * 2048 + i * 512], \
                16, 0, 0);                                                     \
    } while (0)

    STAGE_C(0, 0);
    STAGE_C(1, 64);
    asm volatile("s_waitcnt vmcnt(6)" ::: "memory");
    __builtin_amdgcn_s_barrier();
    __builtin_amdgcn_sched_barrier(0);
    int cur = 0;
    for (int k0 = 0; k0 < 512; k0 += 64) {
#pragma unroll
        for (int kk = 0; kk < 2; ++kk) {
            bh8 af[2], bf[4];
#pragma unroll
            for (int m = 0; m < 2; ++m) {
                const int R = wr * 32 + m * 16 + fr;
                af[m] = *(const bh8*)&As[cur][swz(R, kk * 32 + kg * 8)];
            }
#pragma unroll
            for (int nn = 0; nn < 4; ++nn) {
                const int C = wc * 64 + nn * 16 + fr;
                bf[nn] = *(const bh8*)&Bs[cur][swz(C, kk * 32 + kg * 8)];
            }
#pragma unroll
            for (int m = 0; m < 2; ++m)
#pragma unroll
                for (int nn = 0; nn < 4; ++nn)
                    acc[m][nn] = __builtin_amdgcn_mfma_f32_16x16x32_bf16(
                        af[m], bf[nn], acc[m][nn], 0, 0, 0);
        }
        asm volatile("s_waitcnt lgkmcnt(0)" ::: "memory");
        __builtin_amdgcn_s_barrier();
        __builtin_amdgcn_sched_barrier(0);
        if (k0 + 128 < 512) {
            STAGE_C(cur, k0 + 128);
            asm volatile("s_waitcnt vmcnt(6)" ::: "memory");
        } else if (k0 + 64 < 512) {
            asm volatile("s_waitcnt vmcnt(0)" ::: "memory");
        }
        __builtin_amdgcn_sched_barrier(0);
        cur ^= 1;
    }
#undef STAGE_C
#pragma unroll
    for (int m = 0; m < 2; ++m)
#pragma unroll
        for (int nn = 0; nn < 4; ++nn)
#pragma unroll
            for (int j = 0; j < 4; ++j) {
                const int r = wr * 32 + m * 16 + kg * 4 + j;   // 0..63 = b*NG+i
                const int cc = bn + wc * 64 + nn * 16 + fr;
                const int b = r >> 4, i = r & 15;
                cs[(((size_t)(b * NH) + (cc >> 6)) * NG + i) * DH + (cc & 63)] =
                    acc[m][nn][j];
            }
}

// ---------------------------------------------------------------------------
// QKV MFMA GEMM, fused f32->bf16 of A.  64x128 tile, BK=64, swizzled LDS,
// raw-barrier + counted vmcnt + 2-deep A-register pipeline.  grid (128,4,3).
// NOTE: grid.x must stay ≡ 0 (mod 8): blocks sharing an A-panel (same x,
// different y) sit at linear stride grid.x; stride % 8 == 0 keeps them on
// one XCD so A re-reads hit L2 (R19: stride 129 -> FETCH 42->105 MB).
// ---------------------------------------------------------------------------
__global__ __launch_bounds__(256, 3) void gemm_qkv_kernel(
    const float* __restrict__ qf, const float* __restrict__ kf,
    const float* __restrict__ vf, const ushort* __restrict__ qpT,
    const ushort* __restrict__ kpT, const ushort* __restrict__ vpT,
    ushort* __restrict__ qsb, ushort* __restrict__ ksb, ushort* __restrict__ vsb) {
    const int z = blockIdx.z;
    const float* A32 = (z == 0) ? qf : (z == 1) ? kf : vf;
    const ushort* BT = (z == 0) ? qpT : (z == 1) ? kpT : vpT;
    ushort* out = (z == 0) ? qsb : (z == 1) ? ksb : vsb;

    __shared__ __align__(16) ushort As[2][64 * 64];
    __shared__ __align__(16) ushort Bs[2][128 * 64];
    const int t = threadIdx.x;
    const int lane = t & 63, w = t >> 6;
    const int bm = blockIdx.x * 64, bn = blockIdx.y * 128;
    const int ar = t >> 2, ao = (t & 3) * 16;
    const size_t abase = (size_t)(bm + ar) * 512 + ao;
    const int asw0 = swz(ar, ao), asw1 = swz(ar, ao + 8);
    size_t bsrc[4];
#pragma unroll
    for (int i = 0; i < 4; ++i) {
        const int s = w * 2048 + i * 512 + lane * 8;
        const int r = s >> 6, o = (s & 63) ^ ((r & 7) << 3);
        bsrc[i] = (size_t)(bn + r) * 512 + o;
    }
    const int wr = w >> 1, wc = w & 1;
    const int fr = lane & 15, kg = lane >> 4;
    fx4 acc[2][4] = {};
    float4 a00, a01, a02, a03;   // A register set 0
    float4 a10, a11, a12, a13;   // A register set 1

#define LOADA0(kk)                                                             \
    do {                                                                       \
        a00 = *(const float4*)&A32[abase + (kk)];                              \
        a01 = *(const float4*)&A32[abase + (kk) + 4];                          \
        a02 = *(const float4*)&A32[abase + (kk) + 8];                          \
        a03 = *(const float4*)&A32[abase + (kk) + 12];                         \
    } while (0)
#define LOADA1(kk)                                                             \
    do {                                                                       \
        a10 = *(const float4*)&A32[abase + (kk)];                              \
        a11 = *(const float4*)&A32[abase + (kk) + 4];                          \
        a12 = *(const float4*)&A32[abase + (kk) + 8];                          \
        a13 = *(const float4*)&A32[abase + (kk) + 12];                         \
    } while (0)
#define WRITEA0(buf)                                                           \
    do {                                                                       \
        *(bh8*)&As[buf][asw0] = pack8(a00, a01);                               \
        *(bh8*)&As[buf][asw1] = pack8(a02, a03);                               \
    } while (0)
#define WRITEA1(buf)                                                           \
    do {                                                                       \
        *(bh8*)&As[buf][asw0] = pack8(a10, a11);                               \
        *(bh8*)&As[buf][asw1] = pack8(a12, a13);                               \
    } while (0)
#define STAGEB(buf, kk)                                                        \
    do {                                                                       \
        _Pragma("unroll")                                                      \
        for (int i = 0; i < 4; ++i)                                            \
            __builtin_amdgcn_global_load_lds(                                  \
                (const __attribute__((address_space(1))) void*)(BT + bsrc[i] + (kk)), \
                (__attribute__((address_space(3))) void*)&Bs[buf][w * 2048 + i * 512], \
                16, 0, 0);                                                     \
    } while (0)
#define MFMA_PHASE(buf)                                                        \
    do {                                                                       \
        _Pragma("unroll")                                                      \
        for (int kk = 0; kk < 2; ++kk) {                                       \
            bh8 af[2], bf[4];                                                  \
            _Pragma("unroll")                                                  \
            for (int m = 0; m < 2; ++m) {                                      \
                const int R = wr * 32 + m * 16 + fr;                           \
                af[m] = *(const bh8*)&As[buf][swz(R, kk * 32 + kg * 8)];       \
            }                                                                  \
            _Pragma("unroll")                                                  \
            for (int nn = 0; nn < 4; ++nn) {                                   \
                const int C = wc * 64 + nn * 16 + fr;                          \
                bf[nn] = *(const bh8*)&Bs[buf][swz(C, kk * 32 + kg * 8)];      \
            }                                                                  \
            _Pragma("unroll")                                                  \
            for (int m = 0; m < 2; ++m)                                        \
                _Pragma("unroll")                                              \
                for (int nn = 0; nn < 4; ++nn)                                 \
                    acc[m][nn] = __builtin_amdgcn_mfma_f32_16x16x32_bf16(      \
                        af[m], bf[nn], acc[m][nn], 0, 0, 0);                   \
        }                                                                      \
    } while (0)

    // prologue: buf0 fully staged; B(64) in flight; A(64)->set1, A(128)->set0
    STAGEB(0, 0);
    LOADA0(0);
    WRITEA0(0);                      // compiler drains A(0) loads
    LOADA1(64);
    LOADA0(128);
    STAGEB(1, 64);
    asm volatile("s_waitcnt vmcnt(12) lgkmcnt(0)" ::: "memory");  // B(0) done
    __builtin_amdgcn_s_barrier();
    __builtin_amdgcn_sched_barrier(0);

#pragma unroll
    for (int p = 0; p < 8; ++p) {
        const int k0 = p * 64;
        const int buf = p & 1;
        MFMA_PHASE(buf);
        if (p < 7) {                 // pack A(k0+64), loaded TWO phases ago
            if (((p + 1) & 1) == 0) WRITEA0(buf ^ 1);
            else                    WRITEA1(buf ^ 1);
        }
        asm volatile("s_waitcnt lgkmcnt(0)" ::: "memory");
        __builtin_amdgcn_s_barrier();
        __builtin_amdgcn_sched_barrier(0);
        if (p <= 5) STAGEB(buf, k0 + 128);   // restage buffer just read
        if (p <= 4) {                        // A(k0+192) into freed set
            if (((p + 1) & 1) == 0) LOADA0(k0 + 192);
            else                    LOADA1(k0 + 192);
        }
        if (p <= 4)      asm volatile("s_waitcnt vmcnt(12)" ::: "memory");
        else if (p == 5) asm volatile("s_waitcnt vmcnt(8)" ::: "memory");
        else if (p == 6) asm volatile("s_waitcnt vmcnt(0)" ::: "memory");
        __builtin_amdgcn_sched_barrier(0);
    }
#undef LOADA0
#undef LOADA1
#undef WRITEA0
#undef WRITEA1
#undef STAGEB
#undef MFMA_PHASE
#pragma unroll
    for (int m = 0; m < 2; ++m)
#pragma unroll
        for (int nn = 0; nn < 4; ++nn)
#pragma unroll
            for (int j = 0; j < 4; ++j) {
                const int r = bm + wr * 32 + m * 16 + kg * 4 + j;
                const int cc = bn + wc * 64 + nn * 16 + fr;
                const int b = r >> 11, i = r & 2047;  // SL = 2048
                out[(((size_t)(b * NH) + (cc >> 6)) * SL + i) * DH + (cc & 63)] =
                    f2bf(acc[m][nn][j]);
            }
}

// ---------------------------------------------------------------------------
// Output MFMA GEMM: ohb (8192x512 bf16) @ opT^T -> f32 plain.
// 64x128 tile, BK=64, swizzled LDS, counted-vmcnt pipeline.  grid (128,4).
// ---------------------------------------------------------------------------
__global__ __launch_bounds__(256, 3) void gemm_out_kernel(const ushort* __restrict__ A,
                                                          const ushort* __restrict__ BT,
                                                          float* __restrict__ out) {
    __shared__ __align__(16) ushort As[2][64 * 64];
    __shared__ __align__(16) ushort Bs[2][128 * 64];
    const int t = threadIdx.x;
    const int lane = t & 63, w = t >> 6;
    const int bm = blockIdx.x * 64, bn = blockIdx.y * 128;
    size_t asrc[2], bsrc[4];
#pragma unroll
    for (int i = 0; i < 2; ++i) {
        const int s = w * 1024 + i * 512 + lane * 8;
        const int r = s >> 6, o = (s & 63) ^ ((r & 7) << 3);
        asrc[i] = (size_t)(bm + r) * 512 + o;
    }
#pragma unroll
    for (int i = 0; i < 4; ++i) {
        const int s = w * 2048 + i * 512 + lane * 8;
        const int r = s >> 6, o = (s & 63) ^ ((r & 7) << 3);
        bsrc[i] = (size_t)(bn + r) * 512 + o;
    }
    const int wr = w >> 1, wc = w & 1;
    const int fr = lane & 15, kg = lane >> 4;
    fx4 acc[2][4] = {};

#define STAGE_O(buf, kk)                                                       \
    do {                                                                       \
        _Pragma("unroll")                                                      \
        for (int i = 0; i < 2; ++i)                                            \
            __builtin_amdgcn_global_load_lds(                                  \
                (const __attribute__((address_space(1))) void*)(A + asrc[i] + (kk)), \
                (__attribute__((address_space(3))) void*)&As[buf][w * 1024 + i * 512], \
                16, 0, 0);                                                     \
        _Pragma("unroll")                                                      \
        for (int i = 0; i < 4; ++i)                                            \
            __builtin_amdgcn_global_load_lds(                                  \
                (const __attribute__((address_space(1))) void*)(BT + bsrc[i] + (kk)), \
                (__attribute__((address_space(3))) void*)&Bs[buf][w * 2048 + i * 512], \
                16, 0, 0);                                                     \
    } while (0)

    STAGE_O(0, 0);
    STAGE_O(1, 64);
    asm volatile("s_waitcnt vmcnt(6)" ::: "memory");  // buf0's 6 ops done
    __builtin_amdgcn_s_barrier();
    __builtin_amdgcn_sched_barrier(0);
    int cur = 0;
    for (int k0 = 0; k0 < 512; k0 += 64) {
#pragma unroll
        for (int kk = 0; kk < 2; ++kk) {
            bh8 af[2], bf[4];
#pragma unroll
            for (int m = 0; m < 2; ++m) {
                const int R = wr * 32 + m * 16 + fr;
                af[m] = *(const bh8*)&As[cur][swz(R, kk * 32 + kg * 8)];
            }
#pragma unroll
            for (int nn = 0; nn < 4; ++nn) {
                const int C = wc * 64 + nn * 16 + fr;
                bf[nn] = *(const bh8*)&Bs[cur][swz(C, kk * 32 + kg * 8)];
            }
#pragma unroll
            for (int m = 0; m < 2; ++m)
#pragma unroll
                for (int nn = 0; nn < 4; ++nn)
                    acc[m][nn] = __builtin_amdgcn_mfma_f32_16x16x32_bf16(
                        af[m], bf[nn], acc[m][nn], 0, 0, 0);
        }
        asm volatile("s_waitcnt lgkmcnt(0)" ::: "memory");
        __builtin_amdgcn_s_barrier();
        __builtin_amdgcn_sched_barrier(0);
        if (k0 + 128 < 512) {
            STAGE_O(cur, k0 + 128);
            asm volatile("s_waitcnt vmcnt(6)" ::: "memory");
        } else if (k0 + 64 < 512) {
            asm volatile("s_waitcnt vmcnt(0)" ::: "memory");
        }
        __builtin_amdgcn_sched_barrier(0);
        cur ^= 1;
    }
#undef STAGE_O
#pragma unroll
    for (int m = 0; m < 2; ++m)
#pragma unroll
        for (int nn = 0; nn < 4; ++nn)
#pragma unroll
            for (int j = 0; j < 4; ++j) {
                const int r = bm + wr * 32 + m * 16 + kg * 4 + j;
                const int cc = bn + wc * 64 + nn * 16 + fr;
                out[(size_t)r * 512 + cc] = acc[m][nn][j];
            }
}

// ---------------------------------------------------------------------------
// Fused: W = exp(Ks@Cs^T) -> wb (s,g) + wbT (g,s) + per-chunk sums M_c, N_c.
// grid (NBH, NCH).
// ---------------------------------------------------------------------------
__global__ __launch_bounds__(256) void chunk_sums_w_kernel(
    const ushort* __restrict__ ksb, const ushort* __restrict__ vsb,
    const float* __restrict__ cs, float* __restrict__ wb,
    float* __restrict__ wbT, float* __restrict__ Mc, float* __restrict__ Nc) {
    const int bh = blockIdx.x, c = blockIdx.y;
    __shared__ float Ks[64 * 64];
    __shared__ float Vs[64 * 64];
    __shared__ float Ws[64 * 16];
    __shared__ float Cs[16][65];
    const int t = threadIdx.x;
    const ushort* kbase = ksb + ((size_t)bh * SL + c * 64) * DH;
    const ushort* vbase = vsb + ((size_t)bh * SL + c * 64) * DH;
#pragma unroll
    for (int p = 0; p < 2; ++p) {
        const int idx = (p * 256 + t) * 8;
        float4 lo, hi;
        unpack8(*(const bh8*)&kbase[idx], lo, hi);
        *(float4*)&Ks[idx] = lo; *(float4*)&Ks[idx + 4] = hi;
        unpack8(*(const bh8*)&vbase[idx], lo, hi);
        *(float4*)&Vs[idx] = lo; *(float4*)&Vs[idx + 4] = hi;
    }
    {
        const int idx = t * 4;
        const float4 cv = *(const float4*)&cs[(size_t)bh * NG * DH + idx];
        const int g = idx >> 6, e = idx & 63;
        Cs[g][e + 0] = cv.x; Cs[g][e + 1] = cv.y; Cs[g][e + 2] = cv.z; Cs[g][e + 3] = cv.w;
    }
    __syncthreads();
    {
        const int i = (t * 4) >> 4, g0 = (t * 4) & 15;
        float d0 = 0.f, d1 = 0.f, d2 = 0.f, d3 = 0.f;
#pragma unroll 8
        for (int e = 0; e < 64; ++e) {
            const float kv = Ks[i * 64 + e];
            d0 += kv * Cs[g0 + 0][e];
            d1 += kv * Cs[g0 + 1][e];
            d2 += kv * Cs[g0 + 2][e];
            d3 += kv * Cs[g0 + 3][e];
        }
        float4 wv;
        wv.x = expf(d0); wv.y = expf(d1); wv.z = expf(d2); wv.w = expf(d3);
        *(float4*)&Ws[i * 16 + g0] = wv;
        *(float4*)&wb[((size_t)bh * SL + c * 64 + i) * NG + g0] = wv;
    }
    __syncthreads();
    {
        const int g = t >> 4, i0 = (t & 15) * 4;
        float4 wv4;
        wv4.x = Ws[(i0 + 0) * 16 + g];
        wv4.y = Ws[(i0 + 1) * 16 + g];
        wv4.z = Ws[(i0 + 2) * 16 + g];
        wv4.w = Ws[(i0 + 3) * 16 + g];
        *(float4*)&wbT[((size_t)(bh * NG) + g) * SL + c * 64 + i0] = wv4;
    }
    const int e = t >> 2, g0 = (t & 3) * 4;
    float m0 = 0.f, m1 = 0.f, m2 = 0.f, m3 = 0.f;
#pragma unroll 8
    for (int i = 0; i < 64; ++i) {
        const float kv = Ks[i * 64 + e];
        const float4 w = *(const float4*)&Ws[i * 16 + g0];
        m0 += kv * w.x; m1 += kv * w.y; m2 += kv * w.z; m3 += kv * w.w;
    }
    const int g2 = t >> 4, e2 = (t & 15) * 4;
    float n0 = 0.f, n1 = 0.f, n2 = 0.f, n3 = 0.f;
#pragma unroll 8
    for (int i = 0; i < 64; ++i) {
        const float wv = Ws[i * 16 + g2];
        const float4 vv = *(const float4*)&Vs[i * 64 + e2];
        n0 += wv * vv.x; n1 += wv * vv.y; n2 += wv * vv.z; n3 += wv * vv.w;
    }
    float* mo = Mc + ((size_t)(bh * NCH + c) * 64 + e) * 16 + g0;
    mo[0] = m0; mo[1] = m1; mo[2] = m2; mo[3] = m3;
    float* no = Nc + ((size_t)(bh * NCH + c) * 16 + g2) * 64 + e2;
    no[0] = n0; no[1] = n1; no[2] = n2; no[3] = n3;
}

// ---------------------------------------------------------------------------
// Merged scans.  bid < 512: inclusive cumsum nb over s of wbT — wave-shuffle
// scan, ONE barrier (was 17).  bid >= 512: register-resident exclusive
// chunk-scan of Mc/Nc.
// ---------------------------------------------------------------------------
__global__ __launch_bounds__(256) void scans_kernel(const float* __restrict__ wbT,
                                                    float* __restrict__ nb,
                                                    float* __restrict__ Mc,
                                                    float* __restrict__ Nc) {
    const int bid = blockIdx.x;
    const int t = threadIdx.x;
    if (bid < NBH * NG) {
        const float* src = wbT + (size_t)bid * SL + t * 8;
        float v[8];
        *(float4*)&v[0] = *(const float4*)&src[0];
        *(float4*)&v[4] = *(const float4*)&src[4];
        float loc[8];
        float run = 0.f;
#pragma unroll
        for (int j = 0; j < 8; ++j) { run += v[j]; loc[j] = run; }
        // inclusive wave scan of thread totals (no barriers)
        float s = run;
#pragma unroll
        for (int off = 1; off < 64; off <<= 1) {
            const float u = __shfl_up(s, (unsigned)off, 64);
            if ((t & 63) >= off) s += u;
        }
        __shared__ float wtot[4];
        if ((t & 63) == 63) wtot[t >> 6] = s;
        __syncthreads();
        float wpre = 0.f;
#pragma unroll
        for (int i = 0; i < 3; ++i)
            if (i < (t >> 6)) wpre += wtot[i];
        const float offs = wpre + s - run;   // exclusive prefix for this thread
        float* dst = nb + (size_t)bid * SL + t * 8;
        float o[8];
#pragma unroll
        for (int j = 0; j < 8; ++j) o[j] = offs + loc[j];
        *(float4*)&dst[0] = *(float4*)&o[0];
        *(float4*)&dst[4] = *(float4*)&o[4];
    } else {
        int gid = (bid - NBH * NG) * 256 + t;   // 0..65535 component id
        float* base;
        if (gid < NBH * 1024) base = Mc;
        else { base = Nc; gid -= NBH * 1024; }
        const int st = gid >> 10, comp = gid & 1023;
        float* p = base + (size_t)st * NCH * 1024 + comp;
        float v[NCH];
#pragma unroll
        for (int c = 0; c < NCH; ++c) v[c] = p[(size_t)c * 1024];
        float run = 0.f;
#pragma unroll
        for (int c = 0; c < NCH; ++c) {
            const float x = v[c];
            p[(size_t)c * 1024] = run;
            run += x;
        }
    }
}

// ---------------------------------------------------------------------------
// pass1c: logits = causal(QK^T)@W + Q@P, /n, softmax over g, c = p/(sum*n)
// grid (NBH, NCH).
// ---------------------------------------------------------------------------
__global__ __launch_bounds__(256) void pass1c_kernel(const ushort* __restrict__ qsb,
                                                     const ushort* __restrict__ ksb,
                                                     const float* __restrict__ wb,
                                                     const float* __restrict__ nb,
                                                     const float* __restrict__ Mc,
                                                     float* __restrict__ cb) {
    const int bh = blockIdx.x;
    const int r = blockIdx.y;
    const int s0 = r * 64;
    __shared__ float Qs[64][65];
    __shared__ float Kt[64][65];
    __shared__ float At[64][65];
    __shared__ float Wt[64 * 16];
    __shared__ float Pt[64 * 16];
    __shared__ float Lg[64][17];
    const int t = threadIdx.x;
    const int am = t >> 4, an = t & 15;
    const ushort* qbase = qsb + ((size_t)bh * SL + s0) * DH;
    const ushort* kbase = ksb + ((size_t)bh * SL + s0) * DH;
#pragma unroll
    for (int p = 0; p < 2; ++p) {
        const int idx = (p * 256 + t) * 8;
        const int row = idx >> 6, col = idx & 63;
        float4 lo, hi;
        unpack8(*(const bh8*)&qbase[idx], lo, hi);
        *(float4*)&Qs[row][col] = lo; *(float4*)&Qs[row][col + 4] = hi;
        unpack8(*(const bh8*)&kbase[idx], lo, hi);
        *(float4*)&Kt[row][col] = lo; *(float4*)&Kt[row][col + 4] = hi;
    }
    *(float4*)&Wt[t * 4] = *(const float4*)&wb[((size_t)bh * SL + s0) * NG + t * 4];
    *(float4*)&Pt[t * 4] = *(const float4*)&Mc[(size_t)(bh * NCH + r) * 1024 + t * 4];
    __syncthreads();
    float a[4][4] = {};
#pragma unroll 8
    for (int e = 0; e < 64; ++e) {
        float qv[4], kv[4];
#pragma unroll
        for (int j = 0; j < 4; ++j) qv[j] = Qs[am * 4 + j][e];
#pragma unroll
        for (int jj = 0; jj < 4; ++jj) kv[jj] = Kt[an * 4 + jj][e];
#pragma unroll
        for (int j = 0; j < 4; ++j)
#pragma unroll
            for (int jj = 0; jj < 4; ++jj) a[j][jj] += qv[j] * kv[jj];
    }
#pragma unroll
    for (int j = 0; j < 4; ++j)
#pragma unroll
        for (int jj = 0; jj < 4; ++jj) {
            if (an * 4 + jj > am * 4 + j) a[j][jj] = 0.f;
            At[am * 4 + j][an * 4 + jj] = a[j][jj];
        }
    __syncthreads();
    float lg[4] = {0.f, 0.f, 0.f, 0.f};
#pragma unroll 8
    for (int ii = 0; ii < 64; ++ii) {
        const float wv = Wt[ii * 16 + an];
#pragma unroll
        for (int j = 0; j < 4; ++j) lg[j] += At[am * 4 + j][ii] * wv;
    }
#pragma unroll 8
    for (int e = 0; e < 64; ++e) {
        const float pv = Pt[e * 16 + an];
#pragma unroll
        for (int j = 0; j < 4; ++j) lg[j] += Qs[am * 4 + j][e] * pv;
    }
#pragma unroll
    for (int j = 0; j < 4; ++j) Lg[am * 4 + j][an] = lg[j];
    __syncthreads();
    if (t < 64) {
        const int s = s0 + t;
        const float* nbase = nb + (size_t)bh * NG * SL + s;
        float nv[16], l[16];
        float mx = -1e30f;
#pragma unroll
        for (int g = 0; g < 16; ++g) {
            nv[g] = nbase[(size_t)g * SL];
            l[g] = Lg[t][g] / nv[g];
            mx = fmaxf(mx, l[g]);
        }
        float sum = 0.f;
#pragma unroll
        for (int g = 0; g < 16; ++g) { l[g] = expf(l[g] - mx); sum += l[g]; }
        const float inv = 1.f / sum;
#pragma unroll
        for (int g = 0; g < 16; ++g)
            cb[((size_t)bh * SL + s) * NG + g] = l[g] * inv / nv[g];
    }
}

// ---------------------------------------------------------------------------
// pass2c: out = C@U + causal(C W^T)@V  -> ohb (B,S,512) bf16
// grid (NBH, NCH).
// ---------------------------------------------------------------------------
__global__ __launch_bounds__(256) void pass2c_kernel(const float* __restrict__ cb,
                                                     const float* __restrict__ wb,
                                                     const ushort* __restrict__ vsb,
                                                     const float* __restrict__ Nc,
                                                     ushort* __restrict__ ohb) {
    const int bh = blockIdx.x;
    const int b = bh >> 3, h = bh & 7;
    const int r = blockIdx.y;
    const int s0 = r * 64;
    __shared__ float Ct[64][17];
    __shared__ float Wt[64][17];
    __shared__ float Vt[64 * 64];
    __shared__ float St[64][65];
    __shared__ float Ut[16 * 64];
    const int t = threadIdx.x;
    const int am = t >> 4, an = t & 15;
    {
        const int idx = t * 4;
        const int row = idx >> 4, g0 = idx & 15;
        const float4 cv = *(const float4*)&cb[((size_t)bh * SL + s0) * NG + idx];
        Ct[row][g0 + 0] = cv.x; Ct[row][g0 + 1] = cv.y;
        Ct[row][g0 + 2] = cv.z; Ct[row][g0 + 3] = cv.w;
        const float4 wv = *(const float4*)&wb[((size_t)bh * SL + s0) * NG + idx];
        Wt[row][g0 + 0] = wv.x; Wt[row][g0 + 1] = wv.y;
        Wt[row][g0 + 2] = wv.z; Wt[row][g0 + 3] = wv.w;
    }
    const ushort* vbase = vsb + ((size_t)bh * SL + s0) * DH;
#pragma unroll
    for (int p = 0; p < 2; ++p) {
        const int idx = (p * 256 + t) * 8;
        float4 lo, hi;
        unpack8(*(const bh8*)&vbase[idx], lo, hi);
        *(float4*)&Vt[idx] = lo; *(float4*)&Vt[idx + 4] = hi;
    }
    *(float4*)&Ut[t * 4] = *(const float4*)&Nc[(size_t)(bh * NCH + r) * 1024 + t * 4];
    __syncthreads();
    float sv[4][4] = {};
#pragma unroll
    for (int g = 0; g < 16; ++g) {
        float cv[4], wv[4];
#pragma unroll
        for (int j = 0; j < 4; ++j) cv[j] = Ct[am * 4 + j][g];
#pragma unroll
        for (int jj = 0; jj < 4; ++jj) wv[jj] = Wt[an * 4 + jj][g];
#pragma unroll
        for (int j = 0; j < 4; ++j)
#pragma unroll
            for (int jj = 0; jj < 4; ++jj) sv[j][jj] += cv[j] * wv[jj];
    }
#pragma unroll
    for (int j = 0; j < 4; ++j)
#pragma unroll
        for (int jj = 0; jj < 4; ++jj) {
            if (an * 4 + jj > am * 4 + j) sv[j][jj] = 0.f;
            St[am * 4 + j][an * 4 + jj] = sv[j][jj];
        }
    __syncthreads();
    float acc[4][4] = {};
#pragma unroll
    for (int g = 0; g < 16; ++g) {
        const float4 u = *(const float4*)&Ut[g * 64 + an * 4];
        float cv[4];
#pragma unroll
        for (int j = 0; j < 4; ++j) cv[j] = Ct[am * 4 + j][g];
#pragma unroll
        for (int j = 0; j < 4; ++j) {
            acc[j][0] += cv[j] * u.x; acc[j][1] += cv[j] * u.y;
            acc[j][2] += cv[j] * u.z; acc[j][3] += cv[j] * u.w;
        }
    }
#pragma unroll 8
    for (int ii = 0; ii < 64; ++ii) {
        const float4 vv = *(const float4*)&Vt[ii * 64 + an * 4];
        float st[4];
#pragma unroll
        for (int j = 0; j < 4; ++j) st[j] = St[am * 4 + j][ii];
#pragma unroll
        for (int j = 0; j < 4; ++j) {
            acc[j][0] += st[j] * vv.x; acc[j][1] += st[j] * vv.y;
            acc[j][2] += st[j] * vv.z; acc[j][3] += st[j] * vv.w;
        }
    }
#pragma unroll
    for (int j = 0; j < 4; ++j) {
        const int s = s0 + am * 4 + j;
        ushort4 pk;
        pk.x = f2bf(acc[j][0]); pk.y = f2bf(acc[j][1]);
        pk.z = f2bf(acc[j][2]); pk.w = f2bf(acc[j][3]);
        *(ushort4*)&ohb[((size_t)b * SL + s) * 512 + h * DH + an * 4] = pk;
    }
}

// ---------------------------------------------------------------------------
extern "C" void kernel_launch(void* const* d_in, const int* in_sizes, int n_in,
                              void* d_out, int out_size, void* d_ws, size_t ws_size,
                              hipStream_t stream) {
    const float* query   = (const float*)d_in[0];
    const float* key     = (const float*)d_in[1];
    const float* value   = (const float*)d_in[2];
    const float* context = (const float*)d_in[3];
    const float* qp = (const float*)d_in[4];
    const float* kp = (const float*)d_in[5];
    const float* vp = (const float*)d_in[6];
    const float* op = (const float*)d_in[7];
    const float* cp = (const float*)d_in[8];
    float* out = (float*)d_out;

    // ---- workspace layout (~61 MB, no aliasing) ----
    ushort* qsb = (ushort*)d_ws;            // 4,194,304 ushorts each
    ushort* ksb = qsb + 4194304;
    ushort* vsb = ksb + 4194304;
    ushort* ohb = vsb + 4194304;
    ushort* qpT = ohb + 4194304;            // 262,144 each
    ushort* kpT = qpT + 262144;
    ushort* vpT = kpT + 262144;
    ushort* opT = vpT + 262144;
    ushort* cpT = opT + 262144;             // 262,144
    ushort* ctxb = cpT + 262144;            // 32,768
    float* fbase = (float*)(ctxb + 32768);
    float* cs = fbase;                      // 32,768
    float* wb = cs + 32768;                 // 1,048,576 each
    float* nb = wb + 1048576;
    float* Mc = nb + 1048576;
    float* Nc = Mc + 1048576;
    float* cb = Nc + 1048576;
    float* wbT = cb + 1048576;

    dim3 blk(256);
    prep_kernel<<<dim3(16, 16, 6), blk, 0, stream>>>(qp, kp, vp, op, cp, context,
                                                     qpT, kpT, vpT, opT, cpT, ctxb);
    gemm_ctx_kernel<<<dim3(4), blk, 0, stream>>>(ctxb, cpT, cs);
    gemm_qkv_kernel<<<dim3(128, 4, 3), blk, 0, stream>>>(query, key, value,
                                                         qpT, kpT, vpT, qsb, ksb, vsb);
    chunk_sums_w_kernel<<<dim3(NBH, NCH), blk, 0, stream>>>(ksb, vsb, cs, wb, wbT, Mc, Nc);
    scans_kernel<<<dim3(NBH * NG + 256), blk, 0, stream>>>(wbT, nb, Mc, Nc);
    pass1c_kernel<<<dim3(NBH, NCH), blk, 0, stream>>>(qsb, ksb, wb, nb, Mc, cb);
    pass2c_kernel<<<dim3(NBH, NCH), blk, 0, stream>>>(cb, wb, vsb, Nc, ohb);
    gemm_out_kernel<<<dim3(128, 4), blk, 0, stream>>>(ohb, opT, out);
}